// Round 7
// baseline (868.904 us; speedup 1.0000x reference)
//
#include <hip/hip_runtime.h>
#include <hip/hip_bf16.h>
#include <cstddef>

#define NA 20000
#define NW 100000
#define HH 128
#define DA 64
#define E_CR 400000
#define E_IN 600000
#define E_CO 300000

// combined CSR arena: rows G1(NW) G2(NW) G3(NA) G4(NA)
#define ROW1 0
#define ROW2 (NW)
#define ROW3 (2 * NW)
#define ROW4 (2 * NW + NA)
#define NTOT (2 * NW + 2 * NA)
#define T1 (E_CR + NA)
#define T2 (E_IN + NW)
#define T3 (E_CR + NA)
#define T4 (E_CO + NA)
#define ETOT (T1 + T2 + T3 + T4)

typedef short v8s __attribute__((ext_vector_type(8)));
typedef float v4f __attribute__((ext_vector_type(4)));

constexpr int PSLOT = 128 * 256;  // shorts per plane slot (max K=256)

__device__ inline short f2bf(float x) {
    union { float f; unsigned u; } c; c.f = x;
    unsigned r = c.u + 0x7fff + ((c.u >> 16) & 1);   // RNE
    return (short)(r >> 16);
}
__device__ inline float bf2f(short s) {
    union { unsigned u; float f; } c; c.u = ((unsigned)(unsigned short)s) << 16;
    return c.f;
}

// packed split of 8 floats -> bf16 hi + lo residual (RNE, matches f2bf)
__device__ inline void split8(const float* xv, v8s& h, v8s& l) {
#pragma unroll
    for (int p = 0; p < 4; ++p) {
        float2 xf; xf.x = xv[2 * p]; xf.y = xv[2 * p + 1];
        __hip_bfloat162 hb = __float22bfloat162_rn(xf);
        float2 hf = __bfloat1622float2(hb);
        float2 lf; lf.x = xf.x - hf.x; lf.y = xf.y - hf.y;
        __hip_bfloat162 lb = __float22bfloat162_rn(lf);
        union { __hip_bfloat162 b; short2 s; } uh, ul;
        uh.b = hb; ul.b = lb;
        h[2 * p] = uh.s.x; h[2 * p + 1] = uh.s.y;
        l[2 * p] = ul.s.x; l[2 * p + 1] = ul.s.y;
    }
}

// ---------------- weight prep: split fp32 W[k][n] -> bf16 hi/lo, layout [n][K] ----------
struct PrepDesc { const float* src; int ldw; int K; };
struct PrepArgs { PrepDesc d[10]; const float* wvW; const float* wvA; float* vd; };

__global__ __launch_bounds__(256) void k_prep(PrepArgs a, short* __restrict__ out) {
    if (blockIdx.x == 10 * 128) {   // folded k_wv: vd = cr_W @ cr_ad
        __shared__ float sa[HH];
        int t = threadIdx.x;
        if (t < HH) sa[t] = a.wvA[t];
        __syncthreads();
        if (t < HH) {
            float s = 0.f;
            for (int jj = 0; jj < HH; ++jj) s += a.wvW[(size_t)t * HH + jj] * sa[jj];
            a.vd[t] = s;
        }
        return;
    }
    int m = blockIdx.x >> 7;                        // 128 blocks per matrix
    int e = (blockIdx.x & 127) * 256 + threadIdx.x; // element id
    PrepDesc dd = a.d[m];
    int K = dd.K;
    if (e >= K * 128) return;
    int n = e & 127, k = e >> 7;
    float x = dd.src[(size_t)k * dd.ldw + n];
    short h = f2bf(x);
    short l = f2bf(x - bf2f(h));
    short* base = out + (size_t)m * 2 * PSLOT;
    base[n * K + k] = h;
    base[128 * K + n * K + k] = l;
}

// ---------------- split-bf16 MFMA GEMM, B straight from global (no LDS, no barrier) ----
// Y[M,128] = act(X[M,ldx] @ W[K,128] + b); block = 128 rows, 4 waves x 32 rows.
// NSS: fused per-row dots ss1[r]=dot(o,v1)(+sb), ss2[r]=dot(o,v2). ST=0: skip Y store.
template<int K, int ACT, int NSS, int ST>
__global__ __launch_bounds__(256, 2) void k_mfma(
    const float* __restrict__ X, int ldx,
    const short* __restrict__ Wp,
    const float* __restrict__ bias,
    float* __restrict__ Y, int ldy, int M,
    const float* __restrict__ v1, float* __restrict__ ss1,
    const float* __restrict__ v2, float* __restrict__ ss2,
    const float* __restrict__ sb)
{
    constexpr int KF = K / 32;
    const int tid = threadIdx.x;
    const int wave = tid >> 6, lane = tid & 63;
    const int l15 = lane & 15, quad = lane >> 4;
    const int wrow = blockIdx.x * 128 + wave * 32;

    v4f acc[2][8];
#pragma unroll
    for (int rf = 0; rf < 2; ++rf)
#pragma unroll
        for (int cf = 0; cf < 8; ++cf) acc[rf][cf] = (v4f){0.f, 0.f, 0.f, 0.f};

    for (int kf = 0; kf < KF; ++kf) {
        v8s ah[2], al[2];
#pragma unroll
        for (int rf = 0; rf < 2; ++rf) {
            int r = wrow + rf * 16 + l15; if (r >= M) r = M - 1;
            const float* xp = X + (size_t)r * ldx + kf * 32 + quad * 8;
            float xv[8];
            *(float4*)&xv[0] = *(const float4*)xp;
            *(float4*)&xv[4] = *(const float4*)(xp + 4);
            split8(xv, ah[rf], al[rf]);
        }
#pragma unroll
        for (int cf = 0; cf < 8; ++cf) {
            const short* bp = Wp + (size_t)(cf * 16 + l15) * K + kf * 32 + quad * 8;
            v8s bh = *(const v8s*)bp;
            v8s bl = *(const v8s*)(bp + 128 * K);
#pragma unroll
            for (int rf = 0; rf < 2; ++rf) {
                acc[rf][cf] = __builtin_amdgcn_mfma_f32_16x16x32_bf16(al[rf], bh, acc[rf][cf], 0, 0, 0);
                acc[rf][cf] = __builtin_amdgcn_mfma_f32_16x16x32_bf16(ah[rf], bl, acc[rf][cf], 0, 0, 0);
                acc[rf][cf] = __builtin_amdgcn_mfma_f32_16x16x32_bf16(ah[rf], bh, acc[rf][cf], 0, 0, 0);
            }
        }
    }

    float bv[8], v1c[8], v2c[8];
#pragma unroll
    for (int cf = 0; cf < 8; ++cf) {
        int col = cf * 16 + l15;
        bv[cf] = bias ? bias[col] : 0.f;
        if (NSS >= 1) v1c[cf] = v1[col];
        if (NSS >= 2) v2c[cf] = v2[col];
    }
    float sbv = (NSS >= 1 && sb) ? sb[0] : 0.f;

    // epilogue: C/D layout col=lane&15, row=quad*4+reg
#pragma unroll
    for (int rf = 0; rf < 2; ++rf) {
#pragma unroll
        for (int reg = 0; reg < 4; ++reg) {
            int r = wrow + rf * 16 + quad * 4 + reg;
            if (r >= M) continue;
            float p1 = 0.f, p2 = 0.f;
            float* yp = ST ? (Y + (size_t)r * ldy) : nullptr;
#pragma unroll
            for (int cf = 0; cf < 8; ++cf) {
                float o = acc[rf][cf][reg] + bv[cf];
                if (ACT == 1) o = o > 0.f ? o : 0.f;
                if (NSS >= 1) p1 = fmaf(o, v1c[cf], p1);
                if (NSS >= 2) p2 = fmaf(o, v2c[cf], p2);
                if (ST) yp[cf * 16 + l15] = o;
            }
            if (NSS >= 1) {
#pragma unroll
                for (int w = 1; w < 16; w <<= 1) {
                    p1 += __shfl_xor(p1, w, 64);
                    if (NSS >= 2) p2 += __shfl_xor(p2, w, 64);
                }
                if (l15 == 0) {
                    ss1[r] = p1 + sbv;
                    if (NSS >= 2) ss2[r] = p2;
                }
            }
        }
    }
}

// ---------------- CSR build: all 4 graphs in one pass ----------------
struct EdgeSets { const int* e[4]; int E[4]; int row[4]; int cum[5]; };

__global__ __launch_bounds__(256) void k_hist_all(EdgeSets es, int* __restrict__ deg)
{
    int i = blockIdx.x * 256 + threadIdx.x;
    if (i >= es.cum[4]) return;
    int g = (i >= es.cum[1]) + (i >= es.cum[2]) + (i >= es.cum[3]);
    int t = i - es.cum[g];
    int E = es.E[g];
    int d = (t < E) ? es.e[g][E + t] : (t - E);
    atomicAdd(&deg[es.row[g] + d], 1);
}

__global__ __launch_bounds__(256) void k_scatter_all(EdgeSets es, int* __restrict__ cursor,
                                                    int* __restrict__ esrc)
{
    int i = blockIdx.x * 256 + threadIdx.x;
    if (i >= es.cum[4]) return;
    int g = (i >= es.cum[1]) + (i >= es.cum[2]) + (i >= es.cum[3]);
    int t = i - es.cum[g];
    int E = es.E[g];
    int s, d;
    if (t < E) { s = es.e[g][t]; d = es.e[g][E + t]; }
    else       { s = t - E; d = t - E; }
    int p = atomicAdd(&cursor[es.row[g] + d], 1);
    esrc[p] = s;
}

__global__ void k_scan1(const int* __restrict__ deg, int n,
                        int* __restrict__ rowptr, int* __restrict__ bsum)
{
    __shared__ int sm[256];
    int t = threadIdx.x;
    int i = blockIdx.x * 256 + t;
    int v = (i < n) ? deg[i] : 0;
    int x = v;
    sm[t] = x;
    __syncthreads();
    for (int o = 1; o < 256; o <<= 1) {
        int y = (t >= o) ? sm[t - o] : 0;
        __syncthreads();
        x += y;
        sm[t] = x;
        __syncthreads();
    }
    if (i < n) rowptr[i] = x - v;
    if (t == 255) bsum[blockIdx.x] = x;
}

__global__ void k_scan2(int* __restrict__ bsum, int nb)
{
    __shared__ int sm[256];
    int t = threadIdx.x;
    int base = t * 4;
    int v[4];
    int s = 0;
#pragma unroll
    for (int q = 0; q < 4; ++q) {
        int val = (base + q < nb) ? bsum[base + q] : 0;
        v[q] = s;
        s += val;
    }
    int x = s;
    sm[t] = x;
    __syncthreads();
    for (int o = 1; o < 256; o <<= 1) {
        int y = (t >= o) ? sm[t - o] : 0;
        __syncthreads();
        x += y;
        sm[t] = x;
        __syncthreads();
    }
    int excl = x - s;
#pragma unroll
    for (int q = 0; q < 4; ++q)
        if (base + q < nb) bsum[base + q] = excl + v[q];
}

__global__ void k_scan3(int* __restrict__ rowptr, int* __restrict__ cursor,
                        const int* __restrict__ bsum, int n, int Etot)
{
    int i = blockIdx.x * 256 + threadIdx.x;
    if (i < n) {
        int v = rowptr[i] + bsum[i >> 8];
        rowptr[i] = v;
        cursor[i] = v;
    }
    if (i == 0) rowptr[n] = Etot;
}

// ---------------- GAT aggregation: one dst/wave, float4/lane, 2 edges per pass ----
template<int ELU, int U>
__global__ __launch_bounds__(256) void k_aggregate(
    const int* __restrict__ rowptr, const int* __restrict__ esrc,
    const float* __restrict__ hs, const float* __restrict__ ss,
    const float* __restrict__ sd, const float* __restrict__ bias,
    float* __restrict__ out, int ldy, int n)
{
    int lane = threadIdx.x & 63;
    int wv = threadIdx.x >> 6;
    int d = blockIdx.x * 4 + wv;
    if (d >= n) return;
    int half = lane >> 5;
    int col = (lane & 31) * 4;
    int i0 = rowptr[d], i1 = rowptr[d + 1];
    float sdv = sd[d];
    float den = 0.f;
    float ax = 0.f, ay = 0.f, az = 0.f, aw = 0.f;
    int i = i0;
    for (; i + 2 * U <= i1; i += 2 * U) {
        int s[U]; float4 h[U]; float sv[U];
#pragma unroll
        for (int u = 0; u < U; ++u) s[u] = esrc[i + 2 * u + half];
#pragma unroll
        for (int u = 0; u < U; ++u) h[u] = *(const float4*)(hs + (size_t)s[u] * HH + col);
#pragma unroll
        for (int u = 0; u < U; ++u) sv[u] = ss[s[u]];
#pragma unroll
        for (int u = 0; u < U; ++u) {
            float l = sv[u] + sdv;
            l = l < 0.f ? 0.2f * l : l;
            float e = __expf(l);
            den += e;
            ax = fmaf(e, h[u].x, ax);
            ay = fmaf(e, h[u].y, ay);
            az = fmaf(e, h[u].z, az);
            aw = fmaf(e, h[u].w, aw);
        }
    }
    if (i < i1) {   // masked tail, single pass
        int s[U]; float4 h[U]; float sv[U]; bool act[U];
#pragma unroll
        for (int u = 0; u < U; ++u) {
            int idx = i + 2 * u + half;
            act[u] = idx < i1;
            s[u] = esrc[act[u] ? idx : (i1 - 1)];
        }
#pragma unroll
        for (int u = 0; u < U; ++u) h[u] = *(const float4*)(hs + (size_t)s[u] * HH + col);
#pragma unroll
        for (int u = 0; u < U; ++u) sv[u] = ss[s[u]];
#pragma unroll
        for (int u = 0; u < U; ++u) {
            float l = sv[u] + sdv;
            l = l < 0.f ? 0.2f * l : l;
            float e = act[u] ? __expf(l) : 0.f;
            den += e;
            ax = fmaf(e, h[u].x, ax);
            ay = fmaf(e, h[u].y, ay);
            az = fmaf(e, h[u].z, az);
            aw = fmaf(e, h[u].w, aw);
        }
    }
    den += __shfl_xor(den, 32, 64);
    ax += __shfl_xor(ax, 32, 64);
    ay += __shfl_xor(ay, 32, 64);
    az += __shfl_xor(az, 32, 64);
    aw += __shfl_xor(aw, 32, 64);
    if (half == 0) {
        float4 b = *(const float4*)(bias + col);
        float inv = 1.f / (den + 1e-16f);
        float o0 = ax * inv + b.x;
        float o1 = ay * inv + b.y;
        float o2 = az * inv + b.z;
        float o3 = aw * inv + b.w;
        if (ELU) {
            o0 = o0 > 0.f ? o0 : expm1f(o0);
            o1 = o1 > 0.f ? o1 : expm1f(o1);
            o2 = o2 > 0.f ? o2 : expm1f(o2);
            o3 = o3 > 0.f ? o3 : expm1f(o3);
        }
        v4f o; o[0] = o0; o[1] = o1; o[2] = o2; o[3] = o3;
        __builtin_nontemporal_store(o, (v4f*)(out + (size_t)d * ldy + col));
    }
}

// ---------------- launcher ----------------
extern "C" void kernel_launch(void* const* d_in, const int* in_sizes, int n_in,
                              void* d_out, int out_size, void* d_ws, size_t ws_size,
                              hipStream_t stream)
{
    const float* artist = (const float*)d_in[0];
    const float* workf  = (const float*)d_in[1];
    const float* a_w1 = (const float*)d_in[2];  const float* a_b1 = (const float*)d_in[3];
    const float* a_w2 = (const float*)d_in[4];  const float* a_b2 = (const float*)d_in[5];
    const float* w_w1 = (const float*)d_in[6];  const float* w_b1 = (const float*)d_in[7];
    const float* w_w2 = (const float*)d_in[8];  const float* w_b2 = (const float*)d_in[9];
    const float* cr_W = (const float*)d_in[10]; const float* cr_b = (const float*)d_in[11];
    const float* cr_as = (const float*)d_in[12]; const float* cr_ad = (const float*)d_in[13];
    const float* in_W = (const float*)d_in[14]; const float* in_b = (const float*)d_in[15];
    const float* in_as = (const float*)d_in[16]; const float* in_ad = (const float*)d_in[17];
    const float* co_W = (const float*)d_in[18]; const float* co_b = (const float*)d_in[19];
    const float* co_as = (const float*)d_in[20]; const float* co_ad = (const float*)d_in[21];
    const float* p_w1 = (const float*)d_in[22]; const float* p_b1 = (const float*)d_in[23];
    const float* p_w2 = (const float*)d_in[24]; const float* p_b2 = (const float*)d_in[25];
    const float* p_w3 = (const float*)d_in[26]; const float* p_b3 = (const float*)d_in[27];
    const int* e_cr = (const int*)d_in[28];
    const int* e_cb = (const int*)d_in[29];
    const int* e_in = (const int*)d_in[30];
    const int* e_co = (const int*)d_in[31];

    char* wsp = (char*)d_ws;
    size_t off = 0;
    auto alloc = [&](size_t bytes) -> void* {
        void* p = wsp + off;
        off += (bytes + 255) / 256 * 256;
        return p;
    };
    float* ax   = (float*)alloc((size_t)NA * HH * 4);
    float* wx   = (float*)alloc((size_t)NW * HH * 4);
    float* hs   = (float*)alloc((size_t)NW * HH * 4);   // also h1 [NA,256]
    float* comb = (float*)alloc((size_t)NA * 256 * 4);  // [au | ac]
    float* ss1 = (float*)alloc((size_t)NA * 4);
    float* sd1 = (float*)alloc((size_t)NW * 4);
    float* ss2 = (float*)alloc((size_t)NW * 4);
    float* sd2 = (float*)alloc((size_t)NW * 4);
    float* ss3 = (float*)alloc((size_t)NW * 4);
    float* sd3 = (float*)alloc((size_t)NA * 4);
    float* ss4 = (float*)alloc((size_t)NA * 4);
    float* sd4 = (float*)alloc((size_t)NA * 4);
    float* vd  = (float*)alloc(HH * 4);
    int* rowptr = (int*)alloc((size_t)(NTOT + 1) * 4);
    int* cursor = (int*)alloc((size_t)NTOT * 4);
    int* esrc   = (int*)alloc((size_t)ETOT * 4);
    int* bsum   = (int*)alloc(1024 * 4);
    short* preW = (short*)alloc((size_t)10 * 2 * PSLOT * 2);
    (void)ws_size; (void)in_sizes; (void)n_in; (void)out_size;

    auto pre = [&](int m) { return preW + (size_t)m * 2 * PSLOT; };
    auto gg = [](int M) { return (M + 127) / 128; };
    const float* nf = nullptr;
    float* nfm = nullptr;

    // ---- weight prep (one launch, 10 matrices + folded wv) ----
    PrepArgs pa;
    pa.d[0] = {a_w1, HH, DA};
    pa.d[1] = {a_w2, HH, HH};
    pa.d[2] = {w_w1, HH, HH};
    pa.d[3] = {w_w2, HH, HH};
    pa.d[4] = {cr_W, HH, HH};
    pa.d[5] = {in_W, HH, HH};
    pa.d[6] = {co_W, HH, HH};
    pa.d[7] = {p_w1, 256, 256};         // cols 0-127
    pa.d[8] = {p_w1 + 128, 256, 256};   // cols 128-255
    pa.d[9] = {p_w2, HH, 256};
    pa.wvW = cr_W; pa.wvA = cr_ad; pa.vd = vd;
    k_prep<<<10 * 128 + 1, 256, 0, stream>>>(pa, preW);

    // ---- build all 4 CSRs (2 fused passes + scan) ----
    EdgeSets es;
    es.e[0] = e_cr; es.e[1] = e_in; es.e[2] = e_cb; es.e[3] = e_co;
    es.E[0] = E_CR; es.E[1] = E_IN; es.E[2] = E_CR; es.E[3] = E_CO;
    es.row[0] = ROW1; es.row[1] = ROW2; es.row[2] = ROW3; es.row[3] = ROW4;
    es.cum[0] = 0; es.cum[1] = T1; es.cum[2] = T1 + T2; es.cum[3] = T1 + T2 + T3; es.cum[4] = ETOT;
    hipMemsetAsync(cursor, 0, (size_t)NTOT * 4, stream);
    k_hist_all<<<(ETOT + 255) / 256, 256, 0, stream>>>(es, cursor);
    {
        int nb = (NTOT + 255) / 256;
        k_scan1<<<nb, 256, 0, stream>>>(cursor, NTOT, rowptr, bsum);
        k_scan2<<<1, 256, 0, stream>>>(bsum, nb);
        k_scan3<<<nb, 256, 0, stream>>>(rowptr, cursor, bsum, NTOT, ETOT);
    }
    k_scatter_all<<<(ETOT + 255) / 256, 256, 0, stream>>>(es, cursor, esrc);

    // ---- artist MLP (fused: sd3 = ax @ vd) ----
    k_mfma<DA, 1, 0, 1><<<gg(NA), 256, 0, stream>>>(artist, DA, pre(0), a_b1, hs, HH, NA, nf, nfm, nf, nfm, nf);
    k_mfma<HH, 0, 1, 1><<<gg(NA), 256, 0, stream>>>(hs, HH, pre(1), a_b2, ax, HH, NA, vd, sd3, nf, nfm, nf);
    // ---- work MLP (fused: sd1 = wx @ vd) ----
    k_mfma<HH, 1, 0, 1><<<gg(NW), 256, 0, stream>>>(workf, HH, pre(2), w_b1, hs, HH, NW, nf, nfm, nf, nfm, nf);
    k_mfma<HH, 0, 1, 1><<<gg(NW), 256, 0, stream>>>(hs, HH, pre(3), w_b2, wx, HH, NW, vd, sd1, nf, nfm, nf);

    // ---- GAT1: creates (artists -> works), out wx, ELU ----
    k_mfma<HH, 0, 1, 1><<<gg(NA), 256, 0, stream>>>(ax, HH, pre(4), nullptr, hs, HH, NA, cr_as, ss1, nf, nfm, nf);
    k_aggregate<1, 2><<<(NW + 3) / 4, 256, 0, stream>>>(rowptr + ROW1, esrc, hs, ss1, sd1, cr_b, wx, HH, NW);

    // ---- GAT2: influences (works -> works), out wx, ELU ----
    k_mfma<HH, 0, 2, 1><<<gg(NW), 256, 0, stream>>>(wx, HH, pre(5), nullptr, hs, HH, NW, in_as, ss2, in_ad, sd2, nf);
    k_aggregate<1, 2><<<(NW + 3) / 4, 256, 0, stream>>>(rowptr + ROW2, esrc, hs, ss2, sd2, in_b, wx, HH, NW);

    // ---- GAT3: created_by (works -> artists), out au = comb[:,0:128], NO elu ----
    k_mfma<HH, 0, 1, 1><<<gg(NW), 256, 0, stream>>>(wx, HH, pre(4), nullptr, hs, HH, NW, cr_as, ss3, nf, nfm, nf);
    k_aggregate<0, 4><<<(NA + 3) / 4, 256, 0, stream>>>(rowptr + ROW3, esrc, hs, ss3, sd3, cr_b, comb, 256, NA);

    // ---- GAT4: collab (artists -> artists), out ac = comb[:,128:256], ELU ----
    k_mfma<HH, 0, 2, 1><<<gg(NA), 256, 0, stream>>>(comb, 256, pre(6), nullptr, hs, HH, NA, co_as, ss4, co_ad, sd4, nf);
    k_aggregate<1, 4><<<(NA + 3) / 4, 256, 0, stream>>>(rowptr + ROW4, esrc, hs, ss4, sd4, co_b, comb + 128, 256, NA);

    // ---- predictor: h1 = relu(comb @ p_w1 + b1) [NA,256]; out = relu(h1@p_w2+b2)@p_w3+b3 ----
    float* h1 = hs;
    k_mfma<256, 1, 0, 1><<<gg(NA), 256, 0, stream>>>(comb, 256, pre(7), p_b1, h1, 256, NA, nf, nfm, nf, nfm, nf);
    k_mfma<256, 1, 0, 1><<<gg(NA), 256, 0, stream>>>(comb, 256, pre(8), p_b1 + 128, h1 + 128, 256, NA, nf, nfm, nf, nfm, nf);
    k_mfma<256, 1, 1, 0><<<gg(NA), 256, 0, stream>>>(h1, 256, pre(9), p_b2, nfm, 0, NA, p_w3, (float*)d_out, nf, nfm, p_b3);
}

// Round 8
// 764.392 us; speedup vs baseline: 1.1367x; 1.1367x over previous
//
#include <hip/hip_runtime.h>
#include <hip/hip_bf16.h>
#include <cstddef>

#define NA 20000
#define NW 100000
#define HH 128
#define DA 64
#define E_CR 400000
#define E_IN 600000
#define E_CO 300000

// combined CSR arena: rows G1(NW) G2(NW) G3(NA) G4(NA)
#define ROW1 0
#define ROW2 (NW)
#define ROW3 (2 * NW)
#define ROW4 (2 * NW + NA)
#define NTOT (2 * NW + 2 * NA)
#define T1 (E_CR + NA)
#define T2 (E_IN + NW)
#define T3 (E_CR + NA)
#define T4 (E_CO + NA)
#define ETOT (T1 + T2 + T3 + T4)

typedef short v8s __attribute__((ext_vector_type(8)));
typedef float v4f __attribute__((ext_vector_type(4)));

constexpr int PSLOT = 2 * 128 * 264;  // shorts per matrix slot (covers K=256 and padded K=128)

__device__ inline short f2bf(float x) {
    union { float f; unsigned u; } c; c.f = x;
    unsigned r = c.u + 0x7fff + ((c.u >> 16) & 1);   // RNE
    return (short)(r >> 16);
}
__device__ inline float bf2f(short s) {
    union { unsigned u; float f; } c; c.u = ((unsigned)(unsigned short)s) << 16;
    return c.f;
}

// packed split of 8 floats -> bf16 hi + lo residual (RNE)
__device__ inline void split8(const float* xv, v8s& h, v8s& l) {
#pragma unroll
    for (int p = 0; p < 4; ++p) {
        float2 xf; xf.x = xv[2 * p]; xf.y = xv[2 * p + 1];
        __hip_bfloat162 hb = __float22bfloat162_rn(xf);
        float2 hf = __bfloat1622float2(hb);
        float2 lf; lf.x = xf.x - hf.x; lf.y = xf.y - hf.y;
        __hip_bfloat162 lb = __float22bfloat162_rn(lf);
        union { __hip_bfloat162 b; short2 s; } uh, ul;
        uh.b = hb; ul.b = lb;
        h[2 * p] = uh.s.x; h[2 * p + 1] = uh.s.y;
        l[2 * p] = ul.s.x; l[2 * p + 1] = ul.s.y;
    }
}

// ---------------- weight prep: split fp32 W[k][n] -> bf16 hi/lo planes ----------------
// layout [n][KP] with KP = K+8 for K<=128 (LDS path, pad kills bank conflicts), K for K=256.
struct PrepDesc { const float* src; int ldw; int K; };
struct PrepArgs { PrepDesc d[10]; const float* wvW; const float* wvA; float* vd; };

__global__ __launch_bounds__(256) void k_prep(PrepArgs a, short* __restrict__ out) {
    if (blockIdx.x == 10 * 128) {   // folded: vd = cr_W @ cr_ad
        __shared__ float sa[HH];
        int t = threadIdx.x;
        if (t < HH) sa[t] = a.wvA[t];
        __syncthreads();
        if (t < HH) {
            float s = 0.f;
            for (int jj = 0; jj < HH; ++jj) s += a.wvW[(size_t)t * HH + jj] * sa[jj];
            a.vd[t] = s;
        }
        return;
    }
    int m = blockIdx.x >> 7;
    int e = (blockIdx.x & 127) * 256 + threadIdx.x;
    PrepDesc dd = a.d[m];
    int K = dd.K;
    int KP = (K <= 128) ? K + 8 : K;
    if (e >= K * 128) return;
    int n = e & 127, k = e >> 7;
    float x = dd.src[(size_t)k * dd.ldw + n];
    short h = f2bf(x);
    short l = f2bf(x - bf2f(h));
    short* base = out + (size_t)m * PSLOT;
    base[n * KP + k] = h;
    base[128 * KP + n * KP + k] = l;
}

// ---------------- split-bf16 MFMA GEMM ----------------
// Y[M,128] = act(X[M,ldx] @ W[K,128] + b); block = 128 rows, 4 waves x 32 rows.
// LDSB=1: stage pre-split B planes in LDS (padded KP=K+8, r5-proven). LDSB=0: B from global.
// NSS: fused per-row dots ss1[r]=dot(o,v1)(+sb), ss2[r]=dot(o,v2). ST=0: skip Y store.
template<int K, int ACT, int NSS, int ST, int LDSB>
__global__ __launch_bounds__(256, 2) void k_mfma(
    const float* __restrict__ X, int ldx,
    const short* __restrict__ Wp,
    const float* __restrict__ bias,
    float* __restrict__ Y, int ldy, int M,
    const float* __restrict__ v1, float* __restrict__ ss1,
    const float* __restrict__ v2, float* __restrict__ ss2,
    const float* __restrict__ sb)
{
    constexpr int KF = K / 32;
    constexpr int KP = LDSB ? K + 8 : K;
    __shared__ short Bs[LDSB ? 2 * 128 * (K + 8) : 8];
    const int tid = threadIdx.x;
    const int wave = tid >> 6, lane = tid & 63;
    const int l15 = lane & 15, quad = lane >> 4;
    const int wrow = blockIdx.x * 128 + wave * 32;

    if (LDSB) {
        const float4* src = (const float4*)Wp;
        float4* dst = (float4*)Bs;
        constexpr int total = 2 * 128 * KP / 8;
        for (int i = tid; i < total; i += 256) dst[i] = src[i];
    }

    v4f acc[2][8];
#pragma unroll
    for (int rf = 0; rf < 2; ++rf)
#pragma unroll
        for (int cf = 0; cf < 8; ++cf) acc[rf][cf] = (v4f){0.f, 0.f, 0.f, 0.f};

    if (LDSB) {
        // preload A into registers (overlaps global->LDS staging), then one barrier
        v8s ah[2][KF], al[2][KF];
#pragma unroll
        for (int rf = 0; rf < 2; ++rf) {
            int r = wrow + rf * 16 + l15; if (r >= M) r = M - 1;
            const float* xp = X + (size_t)r * ldx + quad * 8;
#pragma unroll
            for (int kf = 0; kf < KF; ++kf) {
                float xv[8];
                *(float4*)&xv[0] = *(const float4*)(xp + kf * 32);
                *(float4*)&xv[4] = *(const float4*)(xp + kf * 32 + 4);
                split8(xv, ah[rf][kf], al[rf][kf]);
            }
        }
        __syncthreads();
#pragma unroll
        for (int kf = 0; kf < KF; ++kf) {
#pragma unroll
            for (int cf = 0; cf < 8; ++cf) {
                const short* bp = &Bs[(cf * 16 + l15) * KP + kf * 32 + quad * 8];
                v8s bh = *(const v8s*)bp;
                v8s bl = *(const v8s*)(bp + 128 * KP);
#pragma unroll
                for (int rf = 0; rf < 2; ++rf) {
                    acc[rf][cf] = __builtin_amdgcn_mfma_f32_16x16x32_bf16(al[rf][kf], bh, acc[rf][cf], 0, 0, 0);
                    acc[rf][cf] = __builtin_amdgcn_mfma_f32_16x16x32_bf16(ah[rf][kf], bl, acc[rf][cf], 0, 0, 0);
                    acc[rf][cf] = __builtin_amdgcn_mfma_f32_16x16x32_bf16(ah[rf][kf], bh, acc[rf][cf], 0, 0, 0);
                }
            }
        }
    } else {
        for (int kf = 0; kf < KF; ++kf) {
            v8s ah[2], al[2];
#pragma unroll
            for (int rf = 0; rf < 2; ++rf) {
                int r = wrow + rf * 16 + l15; if (r >= M) r = M - 1;
                const float* xp = X + (size_t)r * ldx + kf * 32 + quad * 8;
                float xv[8];
                *(float4*)&xv[0] = *(const float4*)xp;
                *(float4*)&xv[4] = *(const float4*)(xp + 4);
                split8(xv, ah[rf], al[rf]);
            }
#pragma unroll
            for (int cf = 0; cf < 8; ++cf) {
                const short* bp = Wp + (size_t)(cf * 16 + l15) * K + kf * 32 + quad * 8;
                v8s bh = *(const v8s*)bp;
                v8s bl = *(const v8s*)(bp + 128 * KP);
#pragma unroll
                for (int rf = 0; rf < 2; ++rf) {
                    acc[rf][cf] = __builtin_amdgcn_mfma_f32_16x16x32_bf16(al[rf], bh, acc[rf][cf], 0, 0, 0);
                    acc[rf][cf] = __builtin_amdgcn_mfma_f32_16x16x32_bf16(ah[rf], bl, acc[rf][cf], 0, 0, 0);
                    acc[rf][cf] = __builtin_amdgcn_mfma_f32_16x16x32_bf16(ah[rf], bh, acc[rf][cf], 0, 0, 0);
                }
            }
        }
    }

    float bv[8], v1c[8], v2c[8];
#pragma unroll
    for (int cf = 0; cf < 8; ++cf) {
        int col = cf * 16 + l15;
        bv[cf] = bias ? bias[col] : 0.f;
        if (NSS >= 1) v1c[cf] = v1[col];
        if (NSS >= 2) v2c[cf] = v2[col];
    }
    float sbv = (NSS >= 1 && sb) ? sb[0] : 0.f;

    // epilogue: C/D layout col=lane&15, row=quad*4+reg
#pragma unroll
    for (int rf = 0; rf < 2; ++rf) {
#pragma unroll
        for (int reg = 0; reg < 4; ++reg) {
            int r = wrow + rf * 16 + quad * 4 + reg;
            if (r >= M) continue;
            float p1 = 0.f, p2 = 0.f;
            float* yp = ST ? (Y + (size_t)r * ldy) : nullptr;
#pragma unroll
            for (int cf = 0; cf < 8; ++cf) {
                float o = acc[rf][cf][reg] + bv[cf];
                if (ACT == 1) o = o > 0.f ? o : 0.f;
                if (NSS >= 1) p1 = fmaf(o, v1c[cf], p1);
                if (NSS >= 2) p2 = fmaf(o, v2c[cf], p2);
                if (ST) yp[cf * 16 + l15] = o;
            }
            if (NSS >= 1) {
#pragma unroll
                for (int w = 1; w < 16; w <<= 1) {
                    p1 += __shfl_xor(p1, w, 64);
                    if (NSS >= 2) p2 += __shfl_xor(p2, w, 64);
                }
                if (l15 == 0) {
                    ss1[r] = p1 + sbv;
                    if (NSS >= 2) ss2[r] = p2;
                }
            }
        }
    }
}

// ---------------- CSR build: all 4 graphs fused ----------------
struct EdgeSets { const int* e[4]; int E[4]; int row[4]; int cum[5]; };

__global__ __launch_bounds__(256) void k_hist_all(EdgeSets es, int* __restrict__ deg)
{
    int i = blockIdx.x * 256 + threadIdx.x;
    if (i >= es.cum[4]) return;
    int g = (i >= es.cum[1]) + (i >= es.cum[2]) + (i >= es.cum[3]);
    int t = i - es.cum[g];
    int E = es.E[g];
    int d = (t < E) ? es.e[g][E + t] : (t - E);
    atomicAdd(&deg[es.row[g] + d], 1);   // result unused -> fire-and-forget
}

// 4 edges/thread: issue 4 returning atomics back-to-back before any dependent store
__global__ __launch_bounds__(256) void k_scatter_all(EdgeSets es, int* __restrict__ cursor,
                                                    int* __restrict__ esrc)
{
    int b0 = blockIdx.x * 1024 + threadIdx.x;
    int s[4], row[4]; bool ok[4];
#pragma unroll
    for (int u = 0; u < 4; ++u) {
        int i = b0 + u * 256;
        ok[u] = i < es.cum[4];
        s[u] = 0; row[u] = 0;
        if (ok[u]) {
            int g = (i >= es.cum[1]) + (i >= es.cum[2]) + (i >= es.cum[3]);
            int t = i - es.cum[g];
            int E = es.E[g];
            if (t < E) { s[u] = es.e[g][t]; row[u] = es.row[g] + es.e[g][E + t]; }
            else       { s[u] = t - E;      row[u] = es.row[g] + (t - E); }
        }
    }
    int p[4];
#pragma unroll
    for (int u = 0; u < 4; ++u) if (ok[u]) p[u] = atomicAdd(&cursor[row[u]], 1);
#pragma unroll
    for (int u = 0; u < 4; ++u) if (ok[u]) esrc[p[u]] = s[u];
}

__global__ void k_scan1(const int* __restrict__ deg, int n,
                        int* __restrict__ rowptr, int* __restrict__ bsum)
{
    __shared__ int sm[256];
    int t = threadIdx.x;
    int i = blockIdx.x * 256 + t;
    int v = (i < n) ? deg[i] : 0;
    int x = v;
    sm[t] = x;
    __syncthreads();
    for (int o = 1; o < 256; o <<= 1) {
        int y = (t >= o) ? sm[t - o] : 0;
        __syncthreads();
        x += y;
        sm[t] = x;
        __syncthreads();
    }
    if (i < n) rowptr[i] = x - v;
    if (t == 255) bsum[blockIdx.x] = x;
}

__global__ void k_scan2(int* __restrict__ bsum, int nb)
{
    __shared__ int sm[256];
    int t = threadIdx.x;
    int base = t * 4;
    int v[4];
    int s = 0;
#pragma unroll
    for (int q = 0; q < 4; ++q) {
        int val = (base + q < nb) ? bsum[base + q] : 0;
        v[q] = s;
        s += val;
    }
    int x = s;
    sm[t] = x;
    __syncthreads();
    for (int o = 1; o < 256; o <<= 1) {
        int y = (t >= o) ? sm[t - o] : 0;
        __syncthreads();
        x += y;
        sm[t] = x;
        __syncthreads();
    }
    int excl = x - s;
#pragma unroll
    for (int q = 0; q < 4; ++q)
        if (base + q < nb) bsum[base + q] = excl + v[q];
}

__global__ void k_scan3(int* __restrict__ rowptr, int* __restrict__ cursor,
                        const int* __restrict__ bsum, int n, int Etot)
{
    int i = blockIdx.x * 256 + threadIdx.x;
    if (i < n) {
        int v = rowptr[i] + bsum[i >> 8];
        rowptr[i] = v;
        cursor[i] = v;
    }
    if (i == 0) rowptr[n] = Etot;
}

// ---------------- GAT aggregation: one dst/wave, float4/lane, 2 edges per pass ----
template<int ELU, int U>
__global__ __launch_bounds__(256) void k_aggregate(
    const int* __restrict__ rowptr, const int* __restrict__ esrc,
    const float* __restrict__ hs, const float* __restrict__ ss,
    const float* __restrict__ sd, const float* __restrict__ bias,
    float* __restrict__ out, int ldy, int n)
{
    int lane = threadIdx.x & 63;
    int wv = threadIdx.x >> 6;
    int d = blockIdx.x * 4 + wv;
    if (d >= n) return;
    int half = lane >> 5;
    int col = (lane & 31) * 4;
    int i0 = rowptr[d], i1 = rowptr[d + 1];
    float sdv = sd[d];
    float den = 0.f;
    float ax = 0.f, ay = 0.f, az = 0.f, aw = 0.f;
    int i = i0;
    for (; i + 2 * U <= i1; i += 2 * U) {
        int s[U]; float4 h[U]; float sv[U];
#pragma unroll
        for (int u = 0; u < U; ++u) s[u] = esrc[i + 2 * u + half];
#pragma unroll
        for (int u = 0; u < U; ++u) h[u] = *(const float4*)(hs + (size_t)s[u] * HH + col);
#pragma unroll
        for (int u = 0; u < U; ++u) sv[u] = ss[s[u]];
#pragma unroll
        for (int u = 0; u < U; ++u) {
            float l = sv[u] + sdv;
            l = l < 0.f ? 0.2f * l : l;
            float e = __expf(l);
            den += e;
            ax = fmaf(e, h[u].x, ax);
            ay = fmaf(e, h[u].y, ay);
            az = fmaf(e, h[u].z, az);
            aw = fmaf(e, h[u].w, aw);
        }
    }
    if (i < i1) {   // masked tail, single pass
        int s[U]; float4 h[U]; float sv[U]; bool act[U];
#pragma unroll
        for (int u = 0; u < U; ++u) {
            int idx = i + 2 * u + half;
            act[u] = idx < i1;
            s[u] = esrc[act[u] ? idx : (i1 - 1)];
        }
#pragma unroll
        for (int u = 0; u < U; ++u) h[u] = *(const float4*)(hs + (size_t)s[u] * HH + col);
#pragma unroll
        for (int u = 0; u < U; ++u) sv[u] = ss[s[u]];
#pragma unroll
        for (int u = 0; u < U; ++u) {
            float l = sv[u] + sdv;
            l = l < 0.f ? 0.2f * l : l;
            float e = act[u] ? __expf(l) : 0.f;
            den += e;
            ax = fmaf(e, h[u].x, ax);
            ay = fmaf(e, h[u].y, ay);
            az = fmaf(e, h[u].z, az);
            aw = fmaf(e, h[u].w, aw);
        }
    }
    den += __shfl_xor(den, 32, 64);
    ax += __shfl_xor(ax, 32, 64);
    ay += __shfl_xor(ay, 32, 64);
    az += __shfl_xor(az, 32, 64);
    aw += __shfl_xor(aw, 32, 64);
    if (half == 0) {
        float4 b = *(const float4*)(bias + col);
        float inv = 1.f / (den + 1e-16f);
        float o0 = ax * inv + b.x;
        float o1 = ay * inv + b.y;
        float o2 = az * inv + b.z;
        float o3 = aw * inv + b.w;
        if (ELU) {
            o0 = o0 > 0.f ? o0 : expm1f(o0);
            o1 = o1 > 0.f ? o1 : expm1f(o1);
            o2 = o2 > 0.f ? o2 : expm1f(o2);
            o3 = o3 > 0.f ? o3 : expm1f(o3);
        }
        *(float4*)(out + (size_t)d * ldy + col) = make_float4(o0, o1, o2, o3);
    }
}

// ---------------- launcher ----------------
extern "C" void kernel_launch(void* const* d_in, const int* in_sizes, int n_in,
                              void* d_out, int out_size, void* d_ws, size_t ws_size,
                              hipStream_t stream)
{
    const float* artist = (const float*)d_in[0];
    const float* workf  = (const float*)d_in[1];
    const float* a_w1 = (const float*)d_in[2];  const float* a_b1 = (const float*)d_in[3];
    const float* a_w2 = (const float*)d_in[4];  const float* a_b2 = (const float*)d_in[5];
    const float* w_w1 = (const float*)d_in[6];  const float* w_b1 = (const float*)d_in[7];
    const float* w_w2 = (const float*)d_in[8];  const float* w_b2 = (const float*)d_in[9];
    const float* cr_W = (const float*)d_in[10]; const float* cr_b = (const float*)d_in[11];
    const float* cr_as = (const float*)d_in[12]; const float* cr_ad = (const float*)d_in[13];
    const float* in_W = (const float*)d_in[14]; const float* in_b = (const float*)d_in[15];
    const float* in_as = (const float*)d_in[16]; const float* in_ad = (const float*)d_in[17];
    const float* co_W = (const float*)d_in[18]; const float* co_b = (const float*)d_in[19];
    const float* co_as = (const float*)d_in[20]; const float* co_ad = (const float*)d_in[21];
    const float* p_w1 = (const float*)d_in[22]; const float* p_b1 = (const float*)d_in[23];
    const float* p_w2 = (const float*)d_in[24]; const float* p_b2 = (const float*)d_in[25];
    const float* p_w3 = (const float*)d_in[26]; const float* p_b3 = (const float*)d_in[27];
    const int* e_cr = (const int*)d_in[28];
    const int* e_cb = (const int*)d_in[29];
    const int* e_in = (const int*)d_in[30];
    const int* e_co = (const int*)d_in[31];

    char* wsp = (char*)d_ws;
    size_t off = 0;
    auto alloc = [&](size_t bytes) -> void* {
        void* p = wsp + off;
        off += (bytes + 255) / 256 * 256;
        return p;
    };
    float* ax   = (float*)alloc((size_t)NA * HH * 4);
    float* wx   = (float*)alloc((size_t)NW * HH * 4);
    float* hs   = (float*)alloc((size_t)NW * HH * 4);   // also h1 [NA,256]
    float* comb = (float*)alloc((size_t)NA * 256 * 4);  // [au | ac]
    float* ss1 = (float*)alloc((size_t)NA * 4);
    float* sd1 = (float*)alloc((size_t)NW * 4);
    float* ss2 = (float*)alloc((size_t)NW * 4);
    float* sd2 = (float*)alloc((size_t)NW * 4);
    float* ss3 = (float*)alloc((size_t)NW * 4);
    float* sd3 = (float*)alloc((size_t)NA * 4);
    float* ss4 = (float*)alloc((size_t)NA * 4);
    float* sd4 = (float*)alloc((size_t)NA * 4);
    float* vd  = (float*)alloc(HH * 4);
    int* rowptr = (int*)alloc((size_t)(NTOT + 1) * 4);
    int* cursor = (int*)alloc((size_t)NTOT * 4);
    int* esrc   = (int*)alloc((size_t)ETOT * 4);
    int* bsum   = (int*)alloc(1024 * 4);
    short* preW = (short*)alloc((size_t)10 * PSLOT * 2);
    (void)ws_size; (void)in_sizes; (void)n_in; (void)out_size;

    auto pre = [&](int m) { return preW + (size_t)m * PSLOT; };
    auto gg = [](int M) { return (M + 127) / 128; };
    const float* nf = nullptr;
    float* nfm = nullptr;

    // ---- weight prep (one launch, 10 matrices + folded wv) ----
    PrepArgs pa;
    pa.d[0] = {a_w1, HH, DA};
    pa.d[1] = {a_w2, HH, HH};
    pa.d[2] = {w_w1, HH, HH};
    pa.d[3] = {w_w2, HH, HH};
    pa.d[4] = {cr_W, HH, HH};
    pa.d[5] = {in_W, HH, HH};
    pa.d[6] = {co_W, HH, HH};
    pa.d[7] = {p_w1, 256, 256};         // cols 0-127
    pa.d[8] = {p_w1 + 128, 256, 256};   // cols 128-255
    pa.d[9] = {p_w2, HH, 256};
    pa.wvW = cr_W; pa.wvA = cr_ad; pa.vd = vd;
    k_prep<<<10 * 128 + 1, 256, 0, stream>>>(pa, preW);

    // ---- build all 4 CSRs ----
    EdgeSets es;
    es.e[0] = e_cr; es.e[1] = e_in; es.e[2] = e_cb; es.e[3] = e_co;
    es.E[0] = E_CR; es.E[1] = E_IN; es.E[2] = E_CR; es.E[3] = E_CO;
    es.row[0] = ROW1; es.row[1] = ROW2; es.row[2] = ROW3; es.row[3] = ROW4;
    es.cum[0] = 0; es.cum[1] = T1; es.cum[2] = T1 + T2; es.cum[3] = T1 + T2 + T3; es.cum[4] = ETOT;
    (void)hipMemsetAsync(cursor, 0, (size_t)NTOT * 4, stream);
    k_hist_all<<<(ETOT + 255) / 256, 256, 0, stream>>>(es, cursor);
    {
        int nb = (NTOT + 255) / 256;
        k_scan1<<<nb, 256, 0, stream>>>(cursor, NTOT, rowptr, bsum);
        k_scan2<<<1, 256, 0, stream>>>(bsum, nb);
        k_scan3<<<nb, 256, 0, stream>>>(rowptr, cursor, bsum, NTOT, ETOT);
    }
    k_scatter_all<<<(ETOT + 1023) / 1024, 256, 0, stream>>>(es, cursor, esrc);

    // ---- artist MLP (fused: sd3 = ax @ vd) ----
    k_mfma<DA, 1, 0, 1, 1><<<gg(NA), 256, 0, stream>>>(artist, DA, pre(0), a_b1, hs, HH, NA, nf, nfm, nf, nfm, nf);
    k_mfma<HH, 0, 1, 1, 1><<<gg(NA), 256, 0, stream>>>(hs, HH, pre(1), a_b2, ax, HH, NA, vd, sd3, nf, nfm, nf);
    // ---- work MLP (fused: sd1 = wx @ vd) ----
    k_mfma<HH, 1, 0, 1, 1><<<gg(NW), 256, 0, stream>>>(workf, HH, pre(2), w_b1, hs, HH, NW, nf, nfm, nf, nfm, nf);
    k_mfma<HH, 0, 1, 1, 1><<<gg(NW), 256, 0, stream>>>(hs, HH, pre(3), w_b2, wx, HH, NW, vd, sd1, nf, nfm, nf);

    // ---- GAT1: creates (artists -> works), out wx, ELU ----
    k_mfma<HH, 0, 1, 1, 1><<<gg(NA), 256, 0, stream>>>(ax, HH, pre(4), nullptr, hs, HH, NA, cr_as, ss1, nf, nfm, nf);
    k_aggregate<1, 2><<<(NW + 3) / 4, 256, 0, stream>>>(rowptr + ROW1, esrc, hs, ss1, sd1, cr_b, wx, HH, NW);

    // ---- GAT2: influences (works -> works), out wx, ELU ----
    k_mfma<HH, 0, 2, 1, 1><<<gg(NW), 256, 0, stream>>>(wx, HH, pre(5), nullptr, hs, HH, NW, in_as, ss2, in_ad, sd2, nf);
    k_aggregate<1, 2><<<(NW + 3) / 4, 256, 0, stream>>>(rowptr + ROW2, esrc, hs, ss2, sd2, in_b, wx, HH, NW);

    // ---- GAT3: created_by (works -> artists), out au = comb[:,0:128], NO elu ----
    k_mfma<HH, 0, 1, 1, 1><<<gg(NW), 256, 0, stream>>>(wx, HH, pre(4), nullptr, hs, HH, NW, cr_as, ss3, nf, nfm, nf);
    k_aggregate<0, 4><<<(NA + 3) / 4, 256, 0, stream>>>(rowptr + ROW3, esrc, hs, ss3, sd3, cr_b, comb, 256, NA);

    // ---- GAT4: collab (artists -> artists), out ac = comb[:,128:256], ELU ----
    k_mfma<HH, 0, 2, 1, 1><<<gg(NA), 256, 0, stream>>>(comb, 256, pre(6), nullptr, hs, HH, NA, co_as, ss4, co_ad, sd4, nf);
    k_aggregate<1, 4><<<(NA + 3) / 4, 256, 0, stream>>>(rowptr + ROW4, esrc, hs, ss4, sd4, co_b, comb + 128, 256, NA);

    // ---- predictor (K=256, global-B path) ----
    float* h1 = hs;
    k_mfma<256, 1, 0, 1, 0><<<gg(NA), 256, 0, stream>>>(comb, 256, pre(7), p_b1, h1, 256, NA, nf, nfm, nf, nfm, nf);
    k_mfma<256, 1, 0, 1, 0><<<gg(NA), 256, 0, stream>>>(comb, 256, pre(8), p_b1 + 128, h1 + 128, 256, NA, nf, nfm, nf, nfm, nf);
    k_mfma<256, 1, 1, 0, 0><<<gg(NA), 256, 0, stream>>>(h1, 256, pre(9), p_b2, nfm, 0, NA, p_w3, (float*)d_out, nf, nfm, p_b3);
}

// Round 9
// 728.504 us; speedup vs baseline: 1.1927x; 1.0493x over previous
//
#include <hip/hip_runtime.h>
#include <hip/hip_bf16.h>
#include <cstddef>

#define NA 20000
#define NW 100000
#define HH 128
#define DA 64
#define E_CR 400000
#define E_IN 600000
#define E_CO 300000

// combined CSR arena: rows G1(NW) G2(NW) G3(NA) G4(NA); 4 sub-bins per row
#define ROW1 0
#define ROW2 (NW)
#define ROW3 (2 * NW)
#define ROW4 (2 * NW + NA)
#define NTOT (2 * NW + 2 * NA)
#define NB4 (4 * NTOT)
#define T1 (E_CR + NA)
#define T2 (E_IN + NW)
#define T3 (E_CR + NA)
#define T4 (E_CO + NA)
#define ETOT (T1 + T2 + T3 + T4)

typedef short v8s __attribute__((ext_vector_type(8)));
typedef float v4f __attribute__((ext_vector_type(4)));

constexpr int PSLOT = 2 * 128 * 264;  // shorts per matrix slot

__device__ inline short f2bf(float x) {
    union { float f; unsigned u; } c; c.f = x;
    unsigned r = c.u + 0x7fff + ((c.u >> 16) & 1);   // RNE
    return (short)(r >> 16);
}
__device__ inline float bf2f(short s) {
    union { unsigned u; float f; } c; c.u = ((unsigned)(unsigned short)s) << 16;
    return c.f;
}
__device__ inline float bfu2f(unsigned short s) {
    union { unsigned u; float f; } c; c.u = ((unsigned)s) << 16;
    return c.f;
}

// packed split of 8 floats -> bf16 hi + lo residual (RNE)
__device__ inline void split8(const float* xv, v8s& h, v8s& l) {
#pragma unroll
    for (int p = 0; p < 4; ++p) {
        float2 xf; xf.x = xv[2 * p]; xf.y = xv[2 * p + 1];
        __hip_bfloat162 hb = __float22bfloat162_rn(xf);
        float2 hf = __bfloat1622float2(hb);
        float2 lf; lf.x = xf.x - hf.x; lf.y = xf.y - hf.y;
        __hip_bfloat162 lb = __float22bfloat162_rn(lf);
        union { __hip_bfloat162 b; short2 s; } uh, ul;
        uh.b = hb; ul.b = lb;
        h[2 * p] = uh.s.x; h[2 * p + 1] = uh.s.y;
        l[2 * p] = ul.s.x; l[2 * p + 1] = ul.s.y;
    }
}

// ---------------- weight prep ----------------
struct PrepDesc { const float* src; int ldw; int K; };
struct PrepArgs { PrepDesc d[10]; const float* wvW; const float* wvA; float* vd; };

__global__ __launch_bounds__(256) void k_prep(PrepArgs a, short* __restrict__ out) {
    if (blockIdx.x == 10 * 128) {   // folded: vd = cr_W @ cr_ad
        __shared__ float sa[HH];
        int t = threadIdx.x;
        if (t < HH) sa[t] = a.wvA[t];
        __syncthreads();
        if (t < HH) {
            float s = 0.f;
            for (int jj = 0; jj < HH; ++jj) s += a.wvW[(size_t)t * HH + jj] * sa[jj];
            a.vd[t] = s;
        }
        return;
    }
    int m = blockIdx.x >> 7;
    int e = (blockIdx.x & 127) * 256 + threadIdx.x;
    PrepDesc dd = a.d[m];
    int K = dd.K;
    int KP = (K <= 128) ? K + 8 : K;
    if (e >= K * 128) return;
    int n = e & 127, k = e >> 7;
    float x = dd.src[(size_t)k * dd.ldw + n];
    short h = f2bf(x);
    short l = f2bf(x - bf2f(h));
    short* base = out + (size_t)m * PSLOT;
    base[n * KP + k] = h;
    base[128 * KP + n * KP + k] = l;
}

// ---------------- split-bf16 MFMA GEMM ----------------
// LDSB: B planes staged in LDS (padded). OBF: store Y as bf16 (gather table).
// DUAL: second half of grid uses Wp+PSLOT, bias+128, Y+128 (two N=128 panels).
template<int K, int ACT, int NSS, int ST, int LDSB, int OBF, int DUAL>
__global__ __launch_bounds__(256, 2) void k_mfma(
    const float* __restrict__ X, int ldx,
    const short* __restrict__ Wp,
    const float* __restrict__ bias,
    float* __restrict__ Y, int ldy, int M,
    const float* __restrict__ v1, float* __restrict__ ss1,
    const float* __restrict__ v2, float* __restrict__ ss2,
    const float* __restrict__ sb)
{
    constexpr int KF = K / 32;
    constexpr int KP = LDSB ? K + 8 : K;
    __shared__ short Bs[LDSB ? 2 * 128 * (K + 8) : 8];
    const int tid = threadIdx.x;
    const int wave = tid >> 6, lane = tid & 63;
    const int l15 = lane & 15, quad = lane >> 4;
    int bid = blockIdx.x;
    if (DUAL) {
        int g0 = gridDim.x >> 1;
        if (bid >= g0) { bid -= g0; Wp += PSLOT; bias += 128; Y += 128; }
    }
    const int wrow = bid * 128 + wave * 32;

    if (LDSB) {
        const float4* src = (const float4*)Wp;
        float4* dst = (float4*)Bs;
        constexpr int total = 2 * 128 * KP / 8;
        for (int i = tid; i < total; i += 256) dst[i] = src[i];
    }

    v4f acc[2][8];
#pragma unroll
    for (int rf = 0; rf < 2; ++rf)
#pragma unroll
        for (int cf = 0; cf < 8; ++cf) acc[rf][cf] = (v4f){0.f, 0.f, 0.f, 0.f};

    if (LDSB) {
        v8s ah[2][KF], al[2][KF];
#pragma unroll
        for (int rf = 0; rf < 2; ++rf) {
            int r = wrow + rf * 16 + l15; if (r >= M) r = M - 1;
            const float* xp = X + (size_t)r * ldx + quad * 8;
#pragma unroll
            for (int kf = 0; kf < KF; ++kf) {
                float xv[8];
                *(float4*)&xv[0] = *(const float4*)(xp + kf * 32);
                *(float4*)&xv[4] = *(const float4*)(xp + kf * 32 + 4);
                split8(xv, ah[rf][kf], al[rf][kf]);
            }
        }
        __syncthreads();
#pragma unroll
        for (int kf = 0; kf < KF; ++kf) {
#pragma unroll
            for (int cf = 0; cf < 8; ++cf) {
                const short* bp = &Bs[(cf * 16 + l15) * KP + kf * 32 + quad * 8];
                v8s bh = *(const v8s*)bp;
                v8s bl = *(const v8s*)(bp + 128 * KP);
#pragma unroll
                for (int rf = 0; rf < 2; ++rf) {
                    acc[rf][cf] = __builtin_amdgcn_mfma_f32_16x16x32_bf16(al[rf][kf], bh, acc[rf][cf], 0, 0, 0);
                    acc[rf][cf] = __builtin_amdgcn_mfma_f32_16x16x32_bf16(ah[rf][kf], bl, acc[rf][cf], 0, 0, 0);
                    acc[rf][cf] = __builtin_amdgcn_mfma_f32_16x16x32_bf16(ah[rf][kf], bh, acc[rf][cf], 0, 0, 0);
                }
            }
        }
    } else {
        for (int kf = 0; kf < KF; ++kf) {
            v8s ah[2], al[2];
#pragma unroll
            for (int rf = 0; rf < 2; ++rf) {
                int r = wrow + rf * 16 + l15; if (r >= M) r = M - 1;
                const float* xp = X + (size_t)r * ldx + kf * 32 + quad * 8;
                float xv[8];
                *(float4*)&xv[0] = *(const float4*)xp;
                *(float4*)&xv[4] = *(const float4*)(xp + 4);
                split8(xv, ah[rf], al[rf]);
            }
#pragma unroll
            for (int cf = 0; cf < 8; ++cf) {
                const short* bp = Wp + (size_t)(cf * 16 + l15) * K + kf * 32 + quad * 8;
                v8s bh = *(const v8s*)bp;
                v8s bl = *(const v8s*)(bp + 128 * KP);
#pragma unroll
                for (int rf = 0; rf < 2; ++rf) {
                    acc[rf][cf] = __builtin_amdgcn_mfma_f32_16x16x32_bf16(al[rf], bh, acc[rf][cf], 0, 0, 0);
                    acc[rf][cf] = __builtin_amdgcn_mfma_f32_16x16x32_bf16(ah[rf], bl, acc[rf][cf], 0, 0, 0);
                    acc[rf][cf] = __builtin_amdgcn_mfma_f32_16x16x32_bf16(ah[rf], bh, acc[rf][cf], 0, 0, 0);
                }
            }
        }
    }

    float bv[8], v1c[8], v2c[8];
#pragma unroll
    for (int cf = 0; cf < 8; ++cf) {
        int col = cf * 16 + l15;
        bv[cf] = bias ? bias[col] : 0.f;
        if (NSS >= 1) v1c[cf] = v1[col];
        if (NSS >= 2) v2c[cf] = v2[col];
    }
    float sbv = (NSS >= 1 && sb) ? sb[0] : 0.f;

#pragma unroll
    for (int rf = 0; rf < 2; ++rf) {
#pragma unroll
        for (int reg = 0; reg < 4; ++reg) {
            int r = wrow + rf * 16 + quad * 4 + reg;
            if (r >= M) continue;
            float p1 = 0.f, p2 = 0.f;
#pragma unroll
            for (int cf = 0; cf < 8; ++cf) {
                float o = acc[rf][cf][reg] + bv[cf];
                if (ACT == 1) o = o > 0.f ? o : 0.f;
                if (NSS >= 1) p1 = fmaf(o, v1c[cf], p1);
                if (NSS >= 2) p2 = fmaf(o, v2c[cf], p2);
                if (ST) {
                    if (OBF) ((unsigned short*)Y)[(size_t)r * ldy + cf * 16 + l15] = (unsigned short)f2bf(o);
                    else     Y[(size_t)r * ldy + cf * 16 + l15] = o;
                }
            }
            if (NSS >= 1) {
#pragma unroll
                for (int w = 1; w < 16; w <<= 1) {
                    p1 += __shfl_xor(p1, w, 64);
                    if (NSS >= 2) p2 += __shfl_xor(p2, w, 64);
                }
                if (l15 == 0) {
                    ss1[r] = p1 + sbv;
                    if (NSS >= 2) ss2[r] = p2;
                }
            }
        }
    }
}

// ---------------- CSR build: 4 graphs fused, 4 sub-bins/row (contention split) ----
struct EdgeSets { const int* e[4]; int E[4]; int row[4]; int cum[5]; };

__global__ __launch_bounds__(256) void k_hist_all(EdgeSets es, int* __restrict__ deg)
{
    int i = blockIdx.x * 256 + threadIdx.x;
    if (i >= es.cum[4]) return;
    int g = (i >= es.cum[1]) + (i >= es.cum[2]) + (i >= es.cum[3]);
    int t = i - es.cum[g];
    int E = es.E[g];
    int d = (t < E) ? es.e[g][E + t] : (t - E);
    atomicAdd(&deg[4 * (es.row[g] + d) + (i & 3)], 1);
}

__global__ __launch_bounds__(256) void k_scatter_all(EdgeSets es, int* __restrict__ cursor,
                                                    int* __restrict__ esrc)
{
    int b0 = blockIdx.x * 1024 + threadIdx.x;
    int s[4], bin[4]; bool ok[4];
#pragma unroll
    for (int u = 0; u < 4; ++u) {
        int i = b0 + u * 256;
        ok[u] = i < es.cum[4];
        s[u] = 0; bin[u] = 0;
        if (ok[u]) {
            int g = (i >= es.cum[1]) + (i >= es.cum[2]) + (i >= es.cum[3]);
            int t = i - es.cum[g];
            int E = es.E[g];
            int d, sv;
            if (t < E) { sv = es.e[g][t]; d = es.e[g][E + t]; }
            else       { sv = t - E;      d = t - E; }
            s[u] = sv;
            bin[u] = 4 * (es.row[g] + d) + (i & 3);
        }
    }
    int p[4];
#pragma unroll
    for (int u = 0; u < 4; ++u) if (ok[u]) p[u] = atomicAdd(&cursor[bin[u]], 1);
#pragma unroll
    for (int u = 0; u < 4; ++u) if (ok[u]) esrc[p[u]] = s[u];
}

__global__ void k_scan1(const int* __restrict__ deg, int n,
                        int* __restrict__ rowptr, int* __restrict__ bsum)
{
    __shared__ int sm[256];
    int t = threadIdx.x;
    int i = blockIdx.x * 256 + t;
    int v = (i < n) ? deg[i] : 0;
    int x = v;
    sm[t] = x;
    __syncthreads();
    for (int o = 1; o < 256; o <<= 1) {
        int y = (t >= o) ? sm[t - o] : 0;
        __syncthreads();
        x += y;
        sm[t] = x;
        __syncthreads();
    }
    if (i < n) rowptr[i] = x - v;
    if (t == 255) bsum[blockIdx.x] = x;
}

// single-block scan of up to 4096 block sums
__global__ void k_scan2(int* __restrict__ bsum, int nb)
{
    __shared__ int sm[256];
    int t = threadIdx.x;
    int base = t * 16;
    int v[16];
    int s = 0;
#pragma unroll
    for (int q = 0; q < 16; ++q) {
        int val = (base + q < nb) ? bsum[base + q] : 0;
        v[q] = s;
        s += val;
    }
    int x = s;
    sm[t] = x;
    __syncthreads();
    for (int o = 1; o < 256; o <<= 1) {
        int y = (t >= o) ? sm[t - o] : 0;
        __syncthreads();
        x += y;
        sm[t] = x;
        __syncthreads();
    }
    int excl = x - s;
#pragma unroll
    for (int q = 0; q < 16; ++q)
        if (base + q < nb) bsum[base + q] = excl + v[q];
}

__global__ void k_scan3(int* __restrict__ rowptr, int* __restrict__ cursor,
                        const int* __restrict__ bsum, int n, int Etot)
{
    int i = blockIdx.x * 256 + threadIdx.x;
    if (i < n) {
        int v = rowptr[i] + bsum[i >> 8];
        rowptr[i] = v;
        cursor[i] = v;
    }
    if (i == 0) rowptr[n] = Etot;
}

// ---------------- GAT aggregation: bf16 gather table, one dst/wave ----------------
template<int ELU, int U>
__global__ __launch_bounds__(256) void k_aggregate(
    const int* __restrict__ rp4, const int* __restrict__ esrc,
    const unsigned short* __restrict__ hs, const float* __restrict__ ss,
    const float* __restrict__ sd, const float* __restrict__ bias,
    float* __restrict__ out, int ldy, int n)
{
    int lane = threadIdx.x & 63;
    int wv = threadIdx.x >> 6;
    int d = blockIdx.x * 4 + wv;
    if (d >= n) return;
    int half = lane >> 5;
    int col = (lane & 31) * 4;
    int i0 = rp4[4 * d], i1 = rp4[4 * d + 4];
    float sdv = sd[d];
    float den = 0.f;
    float ax = 0.f, ay = 0.f, az = 0.f, aw = 0.f;
    int i = i0;
    for (; i + 2 * U <= i1; i += 2 * U) {
        int s[U]; ushort4 h[U]; float sv[U];
#pragma unroll
        for (int u = 0; u < U; ++u) s[u] = esrc[i + 2 * u + half];
#pragma unroll
        for (int u = 0; u < U; ++u) h[u] = *(const ushort4*)(hs + (size_t)s[u] * HH + col);
#pragma unroll
        for (int u = 0; u < U; ++u) sv[u] = ss[s[u]];
#pragma unroll
        for (int u = 0; u < U; ++u) {
            float l = sv[u] + sdv;
            l = l < 0.f ? 0.2f * l : l;
            float e = __expf(l);
            den += e;
            ax = fmaf(e, bfu2f(h[u].x), ax);
            ay = fmaf(e, bfu2f(h[u].y), ay);
            az = fmaf(e, bfu2f(h[u].z), az);
            aw = fmaf(e, bfu2f(h[u].w), aw);
        }
    }
    if (i < i1) {   // masked tail, single pass
        int s[U]; ushort4 h[U]; float sv[U]; bool act[U];
#pragma unroll
        for (int u = 0; u < U; ++u) {
            int idx = i + 2 * u + half;
            act[u] = idx < i1;
            s[u] = esrc[act[u] ? idx : (i1 - 1)];
        }
#pragma unroll
        for (int u = 0; u < U; ++u) h[u] = *(const ushort4*)(hs + (size_t)s[u] * HH + col);
#pragma unroll
        for (int u = 0; u < U; ++u) sv[u] = ss[s[u]];
#pragma unroll
        for (int u = 0; u < U; ++u) {
            float l = sv[u] + sdv;
            l = l < 0.f ? 0.2f * l : l;
            float e = act[u] ? __expf(l) : 0.f;
            den += e;
            ax = fmaf(e, bfu2f(h[u].x), ax);
            ay = fmaf(e, bfu2f(h[u].y), ay);
            az = fmaf(e, bfu2f(h[u].z), az);
            aw = fmaf(e, bfu2f(h[u].w), aw);
        }
    }
    den += __shfl_xor(den, 32, 64);
    ax += __shfl_xor(ax, 32, 64);
    ay += __shfl_xor(ay, 32, 64);
    az += __shfl_xor(az, 32, 64);
    aw += __shfl_xor(aw, 32, 64);
    if (half == 0) {
        float4 b = *(const float4*)(bias + col);
        float inv = 1.f / (den + 1e-16f);
        float o0 = ax * inv + b.x;
        float o1 = ay * inv + b.y;
        float o2 = az * inv + b.z;
        float o3 = aw * inv + b.w;
        if (ELU) {
            o0 = o0 > 0.f ? o0 : expm1f(o0);
            o1 = o1 > 0.f ? o1 : expm1f(o1);
            o2 = o2 > 0.f ? o2 : expm1f(o2);
            o3 = o3 > 0.f ? o3 : expm1f(o3);
        }
        *(float4*)(out + (size_t)d * ldy + col) = make_float4(o0, o1, o2, o3);
    }
}

// ---------------- launcher ----------------
extern "C" void kernel_launch(void* const* d_in, const int* in_sizes, int n_in,
                              void* d_out, int out_size, void* d_ws, size_t ws_size,
                              hipStream_t stream)
{
    const float* artist = (const float*)d_in[0];
    const float* workf  = (const float*)d_in[1];
    const float* a_w1 = (const float*)d_in[2];  const float* a_b1 = (const float*)d_in[3];
    const float* a_w2 = (const float*)d_in[4];  const float* a_b2 = (const float*)d_in[5];
    const float* w_w1 = (const float*)d_in[6];  const float* w_b1 = (const float*)d_in[7];
    const float* w_w2 = (const float*)d_in[8];  const float* w_b2 = (const float*)d_in[9];
    const float* cr_W = (const float*)d_in[10]; const float* cr_b = (const float*)d_in[11];
    const float* cr_as = (const float*)d_in[12]; const float* cr_ad = (const float*)d_in[13];
    const float* in_W = (const float*)d_in[14]; const float* in_b = (const float*)d_in[15];
    const float* in_as = (const float*)d_in[16]; const float* in_ad = (const float*)d_in[17];
    const float* co_W = (const float*)d_in[18]; const float* co_b = (const float*)d_in[19];
    const float* co_as = (const float*)d_in[20]; const float* co_ad = (const float*)d_in[21];
    const float* p_w1 = (const float*)d_in[22]; const float* p_b1 = (const float*)d_in[23];
    const float* p_w2 = (const float*)d_in[24]; const float* p_b2 = (const float*)d_in[25];
    const float* p_w3 = (const float*)d_in[26]; const float* p_b3 = (const float*)d_in[27];
    const int* e_cr = (const int*)d_in[28];
    const int* e_cb = (const int*)d_in[29];
    const int* e_in = (const int*)d_in[30];
    const int* e_co = (const int*)d_in[31];

    char* wsp = (char*)d_ws;
    size_t off = 0;
    auto alloc = [&](size_t bytes) -> void* {
        void* p = wsp + off;
        off += (bytes + 255) / 256 * 256;
        return p;
    };
    float* ax   = (float*)alloc((size_t)NA * HH * 4);
    float* wx   = (float*)alloc((size_t)NW * HH * 4);
    float* hs   = (float*)alloc((size_t)NW * HH * 4);            // MLP hidden + h1 [NA,256]
    unsigned short* hsb = (unsigned short*)alloc((size_t)NW * HH * 2);  // bf16 gather table
    float* comb = (float*)alloc((size_t)NA * 256 * 4);           // [au | ac]
    float* ss1 = (float*)alloc((size_t)NA * 4);
    float* sd1 = (float*)alloc((size_t)NW * 4);
    float* ss2 = (float*)alloc((size_t)NW * 4);
    float* sd2 = (float*)alloc((size_t)NW * 4);
    float* ss3 = (float*)alloc((size_t)NW * 4);
    float* sd3 = (float*)alloc((size_t)NA * 4);
    float* ss4 = (float*)alloc((size_t)NA * 4);
    float* sd4 = (float*)alloc((size_t)NA * 4);
    float* vd  = (float*)alloc(HH * 4);
    int* rowptr = (int*)alloc((size_t)(NB4 + 1) * 4);
    int* cursor = (int*)alloc((size_t)NB4 * 4);
    int* esrc   = (int*)alloc((size_t)ETOT * 4);
    int* bsum   = (int*)alloc(4096 * 4);
    short* preW = (short*)alloc((size_t)10 * PSLOT * 2);
    (void)ws_size; (void)in_sizes; (void)n_in; (void)out_size;

    auto pre = [&](int m) { return preW + (size_t)m * PSLOT; };
    auto gg = [](int M) { return (M + 127) / 128; };
    const float* nf = nullptr;
    float* nfm = nullptr;

    // ---- weight prep ----
    PrepArgs pa;
    pa.d[0] = {a_w1, HH, DA};
    pa.d[1] = {a_w2, HH, HH};
    pa.d[2] = {w_w1, HH, HH};
    pa.d[3] = {w_w2, HH, HH};
    pa.d[4] = {cr_W, HH, HH};
    pa.d[5] = {in_W, HH, HH};
    pa.d[6] = {co_W, HH, HH};
    pa.d[7] = {p_w1, 256, 256};
    pa.d[8] = {p_w1 + 128, 256, 256};
    pa.d[9] = {p_w2, HH, 256};
    pa.wvW = cr_W; pa.wvA = cr_ad; pa.vd = vd;
    k_prep<<<10 * 128 + 1, 256, 0, stream>>>(pa, preW);

    // ---- build all 4 CSRs (4 sub-bins/row) ----
    EdgeSets es;
    es.e[0] = e_cr; es.e[1] = e_in; es.e[2] = e_cb; es.e[3] = e_co;
    es.E[0] = E_CR; es.E[1] = E_IN; es.E[2] = E_CR; es.E[3] = E_CO;
    es.row[0] = ROW1; es.row[1] = ROW2; es.row[2] = ROW3; es.row[3] = ROW4;
    es.cum[0] = 0; es.cum[1] = T1; es.cum[2] = T1 + T2; es.cum[3] = T1 + T2 + T3; es.cum[4] = ETOT;
    (void)hipMemsetAsync(cursor, 0, (size_t)NB4 * 4, stream);
    k_hist_all<<<(ETOT + 255) / 256, 256, 0, stream>>>(es, cursor);
    {
        int nb = (NB4 + 255) / 256;
        k_scan1<<<nb, 256, 0, stream>>>(cursor, NB4, rowptr, bsum);
        k_scan2<<<1, 256, 0, stream>>>(bsum, nb);
        k_scan3<<<nb, 256, 0, stream>>>(rowptr, cursor, bsum, NB4, ETOT);
    }
    k_scatter_all<<<(ETOT + 1023) / 1024, 256, 0, stream>>>(es, cursor, esrc);

    // ---- artist MLP (fused: sd3 = ax @ vd) ----
    k_mfma<DA, 1, 0, 1, 1, 0, 0><<<gg(NA), 256, 0, stream>>>(artist, DA, pre(0), a_b1, hs, HH, NA, nf, nfm, nf, nfm, nf);
    k_mfma<HH, 0, 1, 1, 1, 0, 0><<<gg(NA), 256, 0, stream>>>(hs, HH, pre(1), a_b2, ax, HH, NA, vd, sd3, nf, nfm, nf);
    // ---- work MLP (fused: sd1 = wx @ vd) ----
    k_mfma<HH, 1, 0, 1, 1, 0, 0><<<gg(NW), 256, 0, stream>>>(workf, HH, pre(2), w_b1, hs, HH, NW, nf, nfm, nf, nfm, nf);
    k_mfma<HH, 0, 1, 1, 1, 0, 0><<<gg(NW), 256, 0, stream>>>(hs, HH, pre(3), w_b2, wx, HH, NW, vd, sd1, nf, nfm, nf);

    // ---- GAT1: creates (artists -> works), out wx, ELU ----
    k_mfma<HH, 0, 1, 1, 1, 1, 0><<<gg(NA), 256, 0, stream>>>(ax, HH, pre(4), nullptr, (float*)hsb, HH, NA, cr_as, ss1, nf, nfm, nf);
    k_aggregate<1, 2><<<(NW + 3) / 4, 256, 0, stream>>>(rowptr + 4 * ROW1, esrc, hsb, ss1, sd1, cr_b, wx, HH, NW);

    // ---- GAT2: influences (works -> works), out wx, ELU ----
    k_mfma<HH, 0, 2, 1, 1, 1, 0><<<gg(NW), 256, 0, stream>>>(wx, HH, pre(5), nullptr, (float*)hsb, HH, NW, in_as, ss2, in_ad, sd2, nf);
    k_aggregate<1, 2><<<(NW + 3) / 4, 256, 0, stream>>>(rowptr + 4 * ROW2, esrc, hsb, ss2, sd2, in_b, wx, HH, NW);

    // ---- GAT3: created_by (works -> artists), out au = comb[:,0:128], NO elu ----
    k_mfma<HH, 0, 1, 1, 1, 1, 0><<<gg(NW), 256, 0, stream>>>(wx, HH, pre(4), nullptr, (float*)hsb, HH, NW, cr_as, ss3, nf, nfm, nf);
    k_aggregate<0, 4><<<(NA + 3) / 4, 256, 0, stream>>>(rowptr + 4 * ROW3, esrc, hsb, ss3, sd3, cr_b, comb, 256, NA);

    // ---- GAT4: collab (artists -> artists), out ac = comb[:,128:256], ELU ----
    k_mfma<HH, 0, 2, 1, 1, 1, 0><<<gg(NA), 256, 0, stream>>>(comb, 256, pre(6), nullptr, (float*)hsb, HH, NA, co_as, ss4, co_ad, sd4, nf);
    k_aggregate<1, 4><<<(NA + 3) / 4, 256, 0, stream>>>(rowptr + 4 * ROW4, esrc, hsb, ss4, sd4, co_b, comb + 128, 256, NA);

    // ---- predictor: h1 dual launch, then fused final layers ----
    float* h1 = hs;
    k_mfma<256, 1, 0, 1, 0, 0, 1><<<2 * gg(NA), 256, 0, stream>>>(comb, 256, pre(7), p_b1, h1, 256, NA, nf, nfm, nf, nfm, nf);
    k_mfma<256, 1, 1, 0, 0, 0, 0><<<gg(NA), 256, 0, stream>>>(h1, 256, pre(9), p_b2, nfm, 0, NA, p_w3, (float*)d_out, nf, nfm, p_b3);
}

// Round 10
// 634.866 us; speedup vs baseline: 1.3686x; 1.1475x over previous
//
#include <hip/hip_runtime.h>
#include <hip/hip_bf16.h>
#include <cstddef>

#define NA 20000
#define NW 100000
#define HH 128
#define DA 64
#define E_CR 400000
#define E_IN 600000
#define E_CO 300000

// deg arena rows: G1(NW) G2(NW) G3(NA) G4(NA)
#define ROW1 0
#define ROW2 (NW)
#define ROW3 (2 * NW)
#define ROW4 (2 * NW + NA)
#define NTOT (2 * NW + 2 * NA)
#define T1 (E_CR + NA)
#define T2 (E_IN + NW)
#define T3 (E_CR + NA)
#define T4 (E_CO + NA)
#define ETOT (T1 + T2 + T3 + T4)
#define CAPW 40   // padded row capacity, NW-dst graphs (mean deg 5/7)
#define CAPA 88   // padded row capacity, NA-dst graphs (mean deg 21/16)

typedef short v8s __attribute__((ext_vector_type(8)));
typedef float v4f __attribute__((ext_vector_type(4)));

constexpr int PSLOT = 2 * 128 * 264;  // shorts per matrix slot

__device__ inline short f2bf(float x) {
    union { float f; unsigned u; } c; c.f = x;
    unsigned r = c.u + 0x7fff + ((c.u >> 16) & 1);   // RNE
    return (short)(r >> 16);
}
__device__ inline float bf2f(short s) {
    union { unsigned u; float f; } c; c.u = ((unsigned)(unsigned short)s) << 16;
    return c.f;
}
__device__ inline float bfu2f(unsigned short s) {
    union { unsigned u; float f; } c; c.u = ((unsigned)s) << 16;
    return c.f;
}

// packed split of 8 floats -> bf16 hi + lo residual (RNE)
__device__ inline void split8(const float* xv, v8s& h, v8s& l) {
#pragma unroll
    for (int p = 0; p < 4; ++p) {
        float2 xf; xf.x = xv[2 * p]; xf.y = xv[2 * p + 1];
        __hip_bfloat162 hb = __float22bfloat162_rn(xf);
        float2 hf = __bfloat1622float2(hb);
        float2 lf; lf.x = xf.x - hf.x; lf.y = xf.y - hf.y;
        __hip_bfloat162 lb = __float22bfloat162_rn(lf);
        union { __hip_bfloat162 b; short2 s; } uh, ul;
        uh.b = hb; ul.b = lb;
        h[2 * p] = uh.s.x; h[2 * p + 1] = uh.s.y;
        l[2 * p] = ul.s.x; l[2 * p + 1] = ul.s.y;
    }
}

// ---------------- weight prep ----------------
struct PrepDesc { const float* src; int ldw; int K; };
struct PrepArgs { PrepDesc d[10]; const float* wvW; const float* wvA; float* vd; };

__global__ __launch_bounds__(256) void k_prep(PrepArgs a, short* __restrict__ out) {
    if (blockIdx.x == 10 * 128) {   // folded: vd = cr_W @ cr_ad
        __shared__ float sa[HH];
        int t = threadIdx.x;
        if (t < HH) sa[t] = a.wvA[t];
        __syncthreads();
        if (t < HH) {
            float s = 0.f;
            for (int jj = 0; jj < HH; ++jj) s += a.wvW[(size_t)t * HH + jj] * sa[jj];
            a.vd[t] = s;
        }
        return;
    }
    int m = blockIdx.x >> 7;
    int e = (blockIdx.x & 127) * 256 + threadIdx.x;
    PrepDesc dd = a.d[m];
    int K = dd.K;
    int KP = (K <= 128) ? K + 8 : K;
    if (e >= K * 128) return;
    int n = e & 127, k = e >> 7;
    float x = dd.src[(size_t)k * dd.ldw + n];
    short h = f2bf(x);
    short l = f2bf(x - bf2f(h));
    short* base = out + (size_t)m * PSLOT;
    base[n * KP + k] = h;
    base[128 * KP + n * KP + k] = l;
}

// ---------------- split-bf16 MFMA GEMM ----------------
// LDSB: B planes staged in LDS (padded). OBF: store Y as bf16 (gather table).
// DUAL: second half of grid uses Wp+PSLOT, bias+128, Y+128.
template<int K, int ACT, int NSS, int ST, int LDSB, int OBF, int DUAL>
__global__ __launch_bounds__(256, 2) void k_mfma(
    const float* __restrict__ X, int ldx,
    const short* __restrict__ Wp,
    const float* __restrict__ bias,
    float* __restrict__ Y, int ldy, int M,
    const float* __restrict__ v1, float* __restrict__ ss1,
    const float* __restrict__ v2, float* __restrict__ ss2,
    const float* __restrict__ sb)
{
    constexpr int KF = K / 32;
    constexpr int KP = LDSB ? K + 8 : K;
    __shared__ short Bs[LDSB ? 2 * 128 * (K + 8) : 8];
    const int tid = threadIdx.x;
    const int wave = tid >> 6, lane = tid & 63;
    const int l15 = lane & 15, quad = lane >> 4;
    int bid = blockIdx.x;
    if (DUAL) {
        int g0 = gridDim.x >> 1;
        if (bid >= g0) { bid -= g0; Wp += PSLOT; bias += 128; Y += 128; }
    }
    const int wrow = bid * 128 + wave * 32;

    if (LDSB) {
        const float4* src = (const float4*)Wp;
        float4* dst = (float4*)Bs;
        constexpr int total = 2 * 128 * KP / 8;
        for (int i = tid; i < total; i += 256) dst[i] = src[i];
    }

    v4f acc[2][8];
#pragma unroll
    for (int rf = 0; rf < 2; ++rf)
#pragma unroll
        for (int cf = 0; cf < 8; ++cf) acc[rf][cf] = (v4f){0.f, 0.f, 0.f, 0.f};

    if (LDSB) {
        v8s ah[2][KF], al[2][KF];
#pragma unroll
        for (int rf = 0; rf < 2; ++rf) {
            int r = wrow + rf * 16 + l15; if (r >= M) r = M - 1;
            const float* xp = X + (size_t)r * ldx + quad * 8;
#pragma unroll
            for (int kf = 0; kf < KF; ++kf) {
                float xv[8];
                *(float4*)&xv[0] = *(const float4*)(xp + kf * 32);
                *(float4*)&xv[4] = *(const float4*)(xp + kf * 32 + 4);
                split8(xv, ah[rf][kf], al[rf][kf]);
            }
        }
        __syncthreads();
#pragma unroll
        for (int kf = 0; kf < KF; ++kf) {
#pragma unroll
            for (int cf = 0; cf < 8; ++cf) {
                const short* bp = &Bs[(cf * 16 + l15) * KP + kf * 32 + quad * 8];
                v8s bh = *(const v8s*)bp;
                v8s bl = *(const v8s*)(bp + 128 * KP);
#pragma unroll
                for (int rf = 0; rf < 2; ++rf) {
                    acc[rf][cf] = __builtin_amdgcn_mfma_f32_16x16x32_bf16(al[rf][kf], bh, acc[rf][cf], 0, 0, 0);
                    acc[rf][cf] = __builtin_amdgcn_mfma_f32_16x16x32_bf16(ah[rf][kf], bl, acc[rf][cf], 0, 0, 0);
                    acc[rf][cf] = __builtin_amdgcn_mfma_f32_16x16x32_bf16(ah[rf][kf], bh, acc[rf][cf], 0, 0, 0);
                }
            }
        }
    } else {
        for (int kf = 0; kf < KF; ++kf) {
            v8s ah[2], al[2];
#pragma unroll
            for (int rf = 0; rf < 2; ++rf) {
                int r = wrow + rf * 16 + l15; if (r >= M) r = M - 1;
                const float* xp = X + (size_t)r * ldx + kf * 32 + quad * 8;
                float xv[8];
                *(float4*)&xv[0] = *(const float4*)xp;
                *(float4*)&xv[4] = *(const float4*)(xp + 4);
                split8(xv, ah[rf], al[rf]);
            }
#pragma unroll
            for (int cf = 0; cf < 8; ++cf) {
                const short* bp = Wp + (size_t)(cf * 16 + l15) * K + kf * 32 + quad * 8;
                v8s bh = *(const v8s*)bp;
                v8s bl = *(const v8s*)(bp + 128 * KP);
#pragma unroll
                for (int rf = 0; rf < 2; ++rf) {
                    acc[rf][cf] = __builtin_amdgcn_mfma_f32_16x16x32_bf16(al[rf], bh, acc[rf][cf], 0, 0, 0);
                    acc[rf][cf] = __builtin_amdgcn_mfma_f32_16x16x32_bf16(ah[rf], bl, acc[rf][cf], 0, 0, 0);
                    acc[rf][cf] = __builtin_amdgcn_mfma_f32_16x16x32_bf16(ah[rf], bh, acc[rf][cf], 0, 0, 0);
                }
            }
        }
    }

    float bv[8], v1c[8], v2c[8];
#pragma unroll
    for (int cf = 0; cf < 8; ++cf) {
        int col = cf * 16 + l15;
        bv[cf] = bias ? bias[col] : 0.f;
        if (NSS >= 1) v1c[cf] = v1[col];
        if (NSS >= 2) v2c[cf] = v2[col];
    }
    float sbv = (NSS >= 1 && sb) ? sb[0] : 0.f;

#pragma unroll
    for (int rf = 0; rf < 2; ++rf) {
#pragma unroll
        for (int reg = 0; reg < 4; ++reg) {
            int r = wrow + rf * 16 + quad * 4 + reg;
            if (r >= M) continue;
            float p1 = 0.f, p2 = 0.f;
#pragma unroll
            for (int cf = 0; cf < 8; ++cf) {
                float o = acc[rf][cf][reg] + bv[cf];
                if (ACT == 1) o = o > 0.f ? o : 0.f;
                if (NSS >= 1) p1 = fmaf(o, v1c[cf], p1);
                if (NSS >= 2) p2 = fmaf(o, v2c[cf], p2);
                if (ST) {
                    if (OBF) ((unsigned short*)Y)[(size_t)r * ldy + cf * 16 + l15] = (unsigned short)f2bf(o);
                    else     Y[(size_t)r * ldy + cf * 16 + l15] = o;
                }
            }
            if (NSS >= 1) {
#pragma unroll
                for (int w = 1; w < 16; w <<= 1) {
                    p1 += __shfl_xor(p1, w, 64);
                    if (NSS >= 2) p2 += __shfl_xor(p2, w, 64);
                }
                if (l15 == 0) {
                    ss1[r] = p1 + sbv;
                    if (NSS >= 2) ss2[r] = p2;
                }
            }
        }
    }
}

// ---------------- padded CSR: single-pass append (no hist, no scan) ----------------
struct EdgeSets { const int* e[4]; int E[4]; int row[4]; int cum[5]; int* pad[4]; int cap[4]; };

__global__ __launch_bounds__(256) void k_append(EdgeSets es, int* __restrict__ deg)
{
    int b0 = blockIdx.x * 1024 + threadIdx.x;
    int s[4], d[4], g[4]; bool ok[4];
#pragma unroll
    for (int u = 0; u < 4; ++u) {
        int i = b0 + u * 256;
        ok[u] = i < es.cum[4];
        s[u] = 0; d[u] = 0; g[u] = 0;
        if (ok[u]) {
            int gi = (i >= es.cum[1]) + (i >= es.cum[2]) + (i >= es.cum[3]);
            int t = i - es.cum[gi];
            int E = es.E[gi];
            if (t < E) { s[u] = es.e[gi][t]; d[u] = es.e[gi][E + t]; }
            else       { s[u] = t - E;       d[u] = t - E; }
            g[u] = gi;
        }
    }
    int p[4];
#pragma unroll
    for (int u = 0; u < 4; ++u) if (ok[u]) p[u] = atomicAdd(&deg[es.row[g[u]] + d[u]], 1);
#pragma unroll
    for (int u = 0; u < 4; ++u)
        if (ok[u] && p[u] < es.cap[g[u]])
            es.pad[g[u]][(size_t)d[u] * es.cap[g[u]] + p[u]] = s[u];
}

// ---------------- GAT aggregation: padded rows, bf16 gather, one dst/wave ----------------
template<int ELU, int U, int CAP>
__global__ __launch_bounds__(256) void k_aggregate(
    const int* __restrict__ deg, const int* __restrict__ esp,
    const unsigned short* __restrict__ hs, const float* __restrict__ ss,
    const float* __restrict__ sd, const float* __restrict__ bias,
    float* __restrict__ out, int ldy, int n)
{
    int lane = threadIdx.x & 63;
    int wv = threadIdx.x >> 6;
    int d = blockIdx.x * 4 + wv;
    if (d >= n) return;
    int half = lane >> 5;
    int col = (lane & 31) * 4;
    const int* row = esp + (size_t)d * CAP;
    int i1 = deg[d]; if (i1 > CAP) i1 = CAP;
    float sdv = sd[d];
    float den = 0.f;
    float ax = 0.f, ay = 0.f, az = 0.f, aw = 0.f;
    int i = 0;
    for (; i + 2 * U <= i1; i += 2 * U) {
        int s[U]; ushort4 h[U]; float sv[U];
#pragma unroll
        for (int u = 0; u < U; ++u) s[u] = row[i + 2 * u + half];
#pragma unroll
        for (int u = 0; u < U; ++u) h[u] = *(const ushort4*)(hs + (size_t)s[u] * HH + col);
#pragma unroll
        for (int u = 0; u < U; ++u) sv[u] = ss[s[u]];
#pragma unroll
        for (int u = 0; u < U; ++u) {
            float l = sv[u] + sdv;
            l = l < 0.f ? 0.2f * l : l;
            float e = __expf(l);
            den += e;
            ax = fmaf(e, bfu2f(h[u].x), ax);
            ay = fmaf(e, bfu2f(h[u].y), ay);
            az = fmaf(e, bfu2f(h[u].z), az);
            aw = fmaf(e, bfu2f(h[u].w), aw);
        }
    }
    if (i < i1) {   // masked tail, single pass
        int s[U]; ushort4 h[U]; float sv[U]; bool act[U];
#pragma unroll
        for (int u = 0; u < U; ++u) {
            int idx = i + 2 * u + half;
            act[u] = idx < i1;
            s[u] = row[act[u] ? idx : (i1 - 1)];
        }
#pragma unroll
        for (int u = 0; u < U; ++u) h[u] = *(const ushort4*)(hs + (size_t)s[u] * HH + col);
#pragma unroll
        for (int u = 0; u < U; ++u) sv[u] = ss[s[u]];
#pragma unroll
        for (int u = 0; u < U; ++u) {
            float l = sv[u] + sdv;
            l = l < 0.f ? 0.2f * l : l;
            float e = act[u] ? __expf(l) : 0.f;
            den += e;
            ax = fmaf(e, bfu2f(h[u].x), ax);
            ay = fmaf(e, bfu2f(h[u].y), ay);
            az = fmaf(e, bfu2f(h[u].z), az);
            aw = fmaf(e, bfu2f(h[u].w), aw);
        }
    }
    den += __shfl_xor(den, 32, 64);
    ax += __shfl_xor(ax, 32, 64);
    ay += __shfl_xor(ay, 32, 64);
    az += __shfl_xor(az, 32, 64);
    aw += __shfl_xor(aw, 32, 64);
    if (half == 0) {
        float4 b = *(const float4*)(bias + col);
        float inv = 1.f / (den + 1e-16f);
        float o0 = ax * inv + b.x;
        float o1 = ay * inv + b.y;
        float o2 = az * inv + b.z;
        float o3 = aw * inv + b.w;
        if (ELU) {
            o0 = o0 > 0.f ? o0 : expm1f(o0);
            o1 = o1 > 0.f ? o1 : expm1f(o1);
            o2 = o2 > 0.f ? o2 : expm1f(o2);
            o3 = o3 > 0.f ? o3 : expm1f(o3);
        }
        *(float4*)(out + (size_t)d * ldy + col) = make_float4(o0, o1, o2, o3);
    }
}

// ---------------- launcher ----------------
extern "C" void kernel_launch(void* const* d_in, const int* in_sizes, int n_in,
                              void* d_out, int out_size, void* d_ws, size_t ws_size,
                              hipStream_t stream)
{
    const float* artist = (const float*)d_in[0];
    const float* workf  = (const float*)d_in[1];
    const float* a_w1 = (const float*)d_in[2];  const float* a_b1 = (const float*)d_in[3];
    const float* a_w2 = (const float*)d_in[4];  const float* a_b2 = (const float*)d_in[5];
    const float* w_w1 = (const float*)d_in[6];  const float* w_b1 = (const float*)d_in[7];
    const float* w_w2 = (const float*)d_in[8];  const float* w_b2 = (const float*)d_in[9];
    const float* cr_W = (const float*)d_in[10]; const float* cr_b = (const float*)d_in[11];
    const float* cr_as = (const float*)d_in[12]; const float* cr_ad = (const float*)d_in[13];
    const float* in_W = (const float*)d_in[14]; const float* in_b = (const float*)d_in[15];
    const float* in_as = (const float*)d_in[16]; const float* in_ad = (const float*)d_in[17];
    const float* co_W = (const float*)d_in[18]; const float* co_b = (const float*)d_in[19];
    const float* co_as = (const float*)d_in[20]; const float* co_ad = (const float*)d_in[21];
    const float* p_w1 = (const float*)d_in[22]; const float* p_b1 = (const float*)d_in[23];
    const float* p_w2 = (const float*)d_in[24]; const float* p_b2 = (const float*)d_in[25];
    const float* p_w3 = (const float*)d_in[26]; const float* p_b3 = (const float*)d_in[27];
    const int* e_cr = (const int*)d_in[28];
    const int* e_cb = (const int*)d_in[29];
    const int* e_in = (const int*)d_in[30];
    const int* e_co = (const int*)d_in[31];

    char* wsp = (char*)d_ws;
    size_t off = 0;
    auto alloc = [&](size_t bytes) -> void* {
        void* p = wsp + off;
        off += (bytes + 255) / 256 * 256;
        return p;
    };
    float* ax   = (float*)alloc((size_t)NA * HH * 4);
    float* wx   = (float*)alloc((size_t)NW * HH * 4);
    float* hs   = (float*)alloc((size_t)NW * HH * 4);            // MLP hidden + h1 [NA,256]
    unsigned short* hsb = (unsigned short*)alloc((size_t)NW * HH * 2);  // bf16 gather table
    float* comb = (float*)alloc((size_t)NA * 256 * 4);           // [au | ac]
    float* ss1 = (float*)alloc((size_t)NA * 4);
    float* sd1 = (float*)alloc((size_t)NW * 4);
    float* ss2 = (float*)alloc((size_t)NW * 4);
    float* sd2 = (float*)alloc((size_t)NW * 4);
    float* ss3 = (float*)alloc((size_t)NW * 4);
    float* sd3 = (float*)alloc((size_t)NA * 4);
    float* ss4 = (float*)alloc((size_t)NA * 4);
    float* sd4 = (float*)alloc((size_t)NA * 4);
    float* vd  = (float*)alloc(HH * 4);
    int* deg   = (int*)alloc((size_t)NTOT * 4);
    int* pad1  = (int*)alloc((size_t)NW * CAPW * 4);
    int* pad2  = (int*)alloc((size_t)NW * CAPW * 4);
    int* pad3  = (int*)alloc((size_t)NA * CAPA * 4);
    int* pad4  = (int*)alloc((size_t)NA * CAPA * 4);
    short* preW = (short*)alloc((size_t)10 * PSLOT * 2);
    (void)ws_size; (void)in_sizes; (void)n_in; (void)out_size;

    auto pre = [&](int m) { return preW + (size_t)m * PSLOT; };
    auto gg = [](int M) { return (M + 127) / 128; };
    const float* nf = nullptr;
    float* nfm = nullptr;

    // ---- single-pass padded CSR append ----
    EdgeSets es;
    es.e[0] = e_cr; es.e[1] = e_in; es.e[2] = e_cb; es.e[3] = e_co;
    es.E[0] = E_CR; es.E[1] = E_IN; es.E[2] = E_CR; es.E[3] = E_CO;
    es.row[0] = ROW1; es.row[1] = ROW2; es.row[2] = ROW3; es.row[3] = ROW4;
    es.cum[0] = 0; es.cum[1] = T1; es.cum[2] = T1 + T2; es.cum[3] = T1 + T2 + T3; es.cum[4] = ETOT;
    es.pad[0] = pad1; es.pad[1] = pad2; es.pad[2] = pad3; es.pad[3] = pad4;
    es.cap[0] = CAPW; es.cap[1] = CAPW; es.cap[2] = CAPA; es.cap[3] = CAPA;
    (void)hipMemsetAsync(deg, 0, (size_t)NTOT * 4, stream);
    k_append<<<(ETOT + 1023) / 1024, 256, 0, stream>>>(es, deg);

    // ---- weight prep ----
    PrepArgs pa;
    pa.d[0] = {a_w1, HH, DA};
    pa.d[1] = {a_w2, HH, HH};
    pa.d[2] = {w_w1, HH, HH};
    pa.d[3] = {w_w2, HH, HH};
    pa.d[4] = {cr_W, HH, HH};
    pa.d[5] = {in_W, HH, HH};
    pa.d[6] = {co_W, HH, HH};
    pa.d[7] = {p_w1, 256, 256};
    pa.d[8] = {p_w1 + 128, 256, 256};
    pa.d[9] = {p_w2, HH, 256};
    pa.wvW = cr_W; pa.wvA = cr_ad; pa.vd = vd;
    k_prep<<<10 * 128 + 1, 256, 0, stream>>>(pa, preW);

    // ---- artist MLP (fused: sd3 = ax @ vd) ----
    k_mfma<DA, 1, 0, 1, 1, 0, 0><<<gg(NA), 256, 0, stream>>>(artist, DA, pre(0), a_b1, hs, HH, NA, nf, nfm, nf, nfm, nf);
    k_mfma<HH, 0, 1, 1, 1, 0, 0><<<gg(NA), 256, 0, stream>>>(hs, HH, pre(1), a_b2, ax, HH, NA, vd, sd3, nf, nfm, nf);
    // ---- work MLP (fused: sd1 = wx @ vd) ----
    k_mfma<HH, 1, 0, 1, 1, 0, 0><<<gg(NW), 256, 0, stream>>>(workf, HH, pre(2), w_b1, hs, HH, NW, nf, nfm, nf, nfm, nf);
    k_mfma<HH, 0, 1, 1, 1, 0, 0><<<gg(NW), 256, 0, stream>>>(hs, HH, pre(3), w_b2, wx, HH, NW, vd, sd1, nf, nfm, nf);

    // ---- GAT1: creates (artists -> works), out wx, ELU ----
    k_mfma<HH, 0, 1, 1, 1, 1, 0><<<gg(NA), 256, 0, stream>>>(ax, HH, pre(4), nullptr, (float*)hsb, HH, NA, cr_as, ss1, nf, nfm, nf);
    k_aggregate<1, 2, CAPW><<<(NW + 3) / 4, 256, 0, stream>>>(deg + ROW1, pad1, hsb, ss1, sd1, cr_b, wx, HH, NW);

    // ---- GAT2: influences (works -> works), out wx, ELU ----
    k_mfma<HH, 0, 2, 1, 1, 1, 0><<<gg(NW), 256, 0, stream>>>(wx, HH, pre(5), nullptr, (float*)hsb, HH, NW, in_as, ss2, in_ad, sd2, nf);
    k_aggregate<1, 2, CAPW><<<(NW + 3) / 4, 256, 0, stream>>>(deg + ROW2, pad2, hsb, ss2, sd2, in_b, wx, HH, NW);

    // ---- GAT3: created_by (works -> artists), out au = comb[:,0:128], NO elu ----
    k_mfma<HH, 0, 1, 1, 1, 1, 0><<<gg(NW), 256, 0, stream>>>(wx, HH, pre(4), nullptr, (float*)hsb, HH, NW, cr_as, ss3, nf, nfm, nf);
    k_aggregate<0, 4, CAPA><<<(NA + 3) / 4, 256, 0, stream>>>(deg + ROW3, pad3, hsb, ss3, sd3, cr_b, comb, 256, NA);

    // ---- GAT4: collab (artists -> artists), out ac = comb[:,128:256], ELU ----
    k_mfma<HH, 0, 2, 1, 1, 1, 0><<<gg(NA), 256, 0, stream>>>(comb, 256, pre(6), nullptr, (float*)hsb, HH, NA, co_as, ss4, co_ad, sd4, nf);
    k_aggregate<1, 4, CAPA><<<(NA + 3) / 4, 256, 0, stream>>>(deg + ROW4, pad4, hsb, ss4, sd4, co_b, comb + 128, 256, NA);

    // ---- predictor: h1 dual launch, then fused final layers ----
    float* h1 = hs;
    k_mfma<256, 1, 0, 1, 0, 0, 1><<<2 * gg(NA), 256, 0, stream>>>(comb, 256, pre(7), p_b1, h1, 256, NA, nf, nfm, nf, nfm, nf);
    k_mfma<256, 1, 1, 0, 0, 0, 0><<<gg(NA), 256, 0, stream>>>(h1, 256, pre(9), p_b2, nfm, 0, NA, p_w3, (float*)d_out, nf, nfm, p_b3);
}

// Round 11
// 617.709 us; speedup vs baseline: 1.4067x; 1.0278x over previous
//
#include <hip/hip_runtime.h>
#include <hip/hip_bf16.h>
#include <cstddef>

#define NA 20000
#define NW 100000
#define HH 128
#define DA 64
#define E_CR 400000
#define E_IN 600000
#define E_CO 300000

// deg arena rows: G1(NW) G2(NW) G3(NA) G4(NA)
#define ROW1 0
#define ROW2 (NW)
#define ROW3 (2 * NW)
#define ROW4 (2 * NW + NA)
#define NTOT (2 * NW + 2 * NA)
#define ETOTR (E_CR + E_IN + E_CR + E_CO)   // real edges only; self-loops handled in aggregate
#define CAPW 40
#define CAPA 88
#define NPREP (10 * 128 + 1)

typedef short v8s __attribute__((ext_vector_type(8)));
typedef float v4f __attribute__((ext_vector_type(4)));

constexpr int PSLOT = 2 * 128 * 264;

__device__ inline short f2bf(float x) {
    union { float f; unsigned u; } c; c.f = x;
    unsigned r = c.u + 0x7fff + ((c.u >> 16) & 1);   // RNE
    return (short)(r >> 16);
}
__device__ inline float bf2f(short s) {
    union { unsigned u; float f; } c; c.u = ((unsigned)(unsigned short)s) << 16;
    return c.f;
}
__device__ inline float bfu2f(unsigned short s) {
    union { unsigned u; float f; } c; c.u = ((unsigned)s) << 16;
    return c.f;
}

__device__ inline void split8(const float* xv, v8s& h, v8s& l) {
#pragma unroll
    for (int p = 0; p < 4; ++p) {
        float2 xf; xf.x = xv[2 * p]; xf.y = xv[2 * p + 1];
        __hip_bfloat162 hb = __float22bfloat162_rn(xf);
        float2 hf = __bfloat1622float2(hb);
        float2 lf; lf.x = xf.x - hf.x; lf.y = xf.y - hf.y;
        __hip_bfloat162 lb = __float22bfloat162_rn(lf);
        union { __hip_bfloat162 b; short2 s; } uh, ul;
        uh.b = hb; ul.b = lb;
        h[2 * p] = uh.s.x; h[2 * p + 1] = uh.s.y;
        l[2 * p] = ul.s.x; l[2 * p + 1] = ul.s.y;
    }
}

// ---------------- fused weight-prep + padded-CSR append ----------------
struct PrepDesc { const float* src; int ldw; int K; };
struct PrepArgs { PrepDesc d[10]; const float* wvW; const float* wvA; float* vd; };
struct EdgeSets { const int* e[4]; int E[4]; int row[4]; int cum[5]; int* pad[4]; int cap[4]; };

__global__ __launch_bounds__(256) void k_prep_append(PrepArgs a, short* __restrict__ out,
                                                    EdgeSets es, int* __restrict__ deg)
{
    if (blockIdx.x < NPREP) {
        if (blockIdx.x == NPREP - 1) {   // folded: vd = cr_W @ cr_ad
            __shared__ float sa[HH];
            int t = threadIdx.x;
            if (t < HH) sa[t] = a.wvA[t];
            __syncthreads();
            if (t < HH) {
                float s = 0.f;
                for (int jj = 0; jj < HH; ++jj) s += a.wvW[(size_t)t * HH + jj] * sa[jj];
                a.vd[t] = s;
            }
            return;
        }
        int m = blockIdx.x >> 7;
        int e = (blockIdx.x & 127) * 256 + threadIdx.x;
        PrepDesc dd = a.d[m];
        int K = dd.K;
        int KP = (K <= 128) ? K + 8 : K;
        if (e >= K * 128) return;
        int n = e & 127, k = e >> 7;
        float x = dd.src[(size_t)k * dd.ldw + n];
        short h = f2bf(x);
        short l = f2bf(x - bf2f(h));
        short* base = out + (size_t)m * PSLOT;
        base[n * KP + k] = h;
        base[128 * KP + n * KP + k] = l;
        return;
    }
    // ---- append: real edges only, 4 per thread ----
    int b0 = (blockIdx.x - NPREP) * 1024 + threadIdx.x;
    int s[4], d[4], g[4]; bool ok[4];
#pragma unroll
    for (int u = 0; u < 4; ++u) {
        int i = b0 + u * 256;
        ok[u] = i < es.cum[4];
        s[u] = 0; d[u] = 0; g[u] = 0;
        if (ok[u]) {
            int gi = (i >= es.cum[1]) + (i >= es.cum[2]) + (i >= es.cum[3]);
            int t = i - es.cum[gi];
            s[u] = es.e[gi][t];
            d[u] = es.e[gi][es.E[gi] + t];
            g[u] = gi;
        }
    }
    int p[4];
#pragma unroll
    for (int u = 0; u < 4; ++u) if (ok[u]) p[u] = atomicAdd(&deg[es.row[g[u]] + d[u]], 1);
#pragma unroll
    for (int u = 0; u < 4; ++u)
        if (ok[u] && p[u] < es.cap[g[u]])
            es.pad[g[u]][(size_t)d[u] * es.cap[g[u]] + p[u]] = s[u];
}

// ---------------- split-bf16 MFMA GEMM (compile-time config; r10-proven) ----------------
template<int K, int ACT, int NSS, int ST, int LDSB, int OBF, int DUAL>
__global__ __launch_bounds__(256, 2) void k_mfma(
    const float* __restrict__ X, int ldx,
    const short* __restrict__ Wp,
    const float* __restrict__ bias,
    float* __restrict__ Y, int ldy, int M,
    const float* __restrict__ v1, float* __restrict__ ss1,
    const float* __restrict__ v2, float* __restrict__ ss2,
    const float* __restrict__ sb)
{
    constexpr int KF = K / 32;
    constexpr int KP = LDSB ? K + 8 : K;
    __shared__ short Bs[LDSB ? 2 * 128 * (K + 8) : 8];
    const int tid = threadIdx.x;
    const int wave = tid >> 6, lane = tid & 63;
    const int l15 = lane & 15, quad = lane >> 4;
    int bid = blockIdx.x;
    if (DUAL) {
        int g0 = gridDim.x >> 1;
        if (bid >= g0) { bid -= g0; Wp += PSLOT; bias += 128; Y += 128; }
    }
    const int wrow = bid * 128 + wave * 32;

    if (LDSB) {
        const float4* src = (const float4*)Wp;
        float4* dst = (float4*)Bs;
        constexpr int total = 2 * 128 * KP / 8;
        for (int i = tid; i < total; i += 256) dst[i] = src[i];
    }

    v4f acc[2][8];
#pragma unroll
    for (int rf = 0; rf < 2; ++rf)
#pragma unroll
        for (int cf = 0; cf < 8; ++cf) acc[rf][cf] = (v4f){0.f, 0.f, 0.f, 0.f};

    if (LDSB) {
        v8s ah[2][KF], al[2][KF];
#pragma unroll
        for (int rf = 0; rf < 2; ++rf) {
            int r = wrow + rf * 16 + l15; if (r >= M) r = M - 1;
            const float* xp = X + (size_t)r * ldx + quad * 8;
#pragma unroll
            for (int kf = 0; kf < KF; ++kf) {
                float xv[8];
                *(float4*)&xv[0] = *(const float4*)(xp + kf * 32);
                *(float4*)&xv[4] = *(const float4*)(xp + kf * 32 + 4);
                split8(xv, ah[rf][kf], al[rf][kf]);
            }
        }
        __syncthreads();
#pragma unroll
        for (int kf = 0; kf < KF; ++kf) {
#pragma unroll
            for (int cf = 0; cf < 8; ++cf) {
                const short* bp = &Bs[(cf * 16 + l15) * KP + kf * 32 + quad * 8];
                v8s bh = *(const v8s*)bp;
                v8s bl = *(const v8s*)(bp + 128 * KP);
#pragma unroll
                for (int rf = 0; rf < 2; ++rf) {
                    acc[rf][cf] = __builtin_amdgcn_mfma_f32_16x16x32_bf16(al[rf][kf], bh, acc[rf][cf], 0, 0, 0);
                    acc[rf][cf] = __builtin_amdgcn_mfma_f32_16x16x32_bf16(ah[rf][kf], bl, acc[rf][cf], 0, 0, 0);
                    acc[rf][cf] = __builtin_amdgcn_mfma_f32_16x16x32_bf16(ah[rf][kf], bh, acc[rf][cf], 0, 0, 0);
                }
            }
        }
    } else {
        for (int kf = 0; kf < KF; ++kf) {
            v8s ah[2], al[2];
#pragma unroll
            for (int rf = 0; rf < 2; ++rf) {
                int r = wrow + rf * 16 + l15; if (r >= M) r = M - 1;
                const float* xp = X + (size_t)r * ldx + kf * 32 + quad * 8;
                float xv[8];
                *(float4*)&xv[0] = *(const float4*)xp;
                *(float4*)&xv[4] = *(const float4*)(xp + 4);
                split8(xv, ah[rf], al[rf]);
            }
#pragma unroll
            for (int cf = 0; cf < 8; ++cf) {
                const short* bp = Wp + (size_t)(cf * 16 + l15) * K + kf * 32 + quad * 8;
                v8s bh = *(const v8s*)bp;
                v8s bl = *(const v8s*)(bp + 128 * KP);
#pragma unroll
                for (int rf = 0; rf < 2; ++rf) {
                    acc[rf][cf] = __builtin_amdgcn_mfma_f32_16x16x32_bf16(al[rf], bh, acc[rf][cf], 0, 0, 0);
                    acc[rf][cf] = __builtin_amdgcn_mfma_f32_16x16x32_bf16(ah[rf], bl, acc[rf][cf], 0, 0, 0);
                    acc[rf][cf] = __builtin_amdgcn_mfma_f32_16x16x32_bf16(ah[rf], bh, acc[rf][cf], 0, 0, 0);
                }
            }
        }
    }

    float bv[8], v1c[8], v2c[8];
#pragma unroll
    for (int cf = 0; cf < 8; ++cf) {
        int col = cf * 16 + l15;
        bv[cf] = bias ? bias[col] : 0.f;
        if (NSS >= 1) v1c[cf] = v1[col];
        if (NSS >= 2) v2c[cf] = v2[col];
    }
    float sbv = (NSS >= 1 && sb) ? sb[0] : 0.f;

#pragma unroll
    for (int rf = 0; rf < 2; ++rf) {
#pragma unroll
        for (int reg = 0; reg < 4; ++reg) {
            int r = wrow + rf * 16 + quad * 4 + reg;
            if (r >= M) continue;
            float p1 = 0.f, p2 = 0.f;
#pragma unroll
            for (int cf = 0; cf < 8; ++cf) {
                float o = acc[rf][cf][reg] + bv[cf];
                if (ACT == 1) o = o > 0.f ? o : 0.f;
                if (NSS >= 1) p1 = fmaf(o, v1c[cf], p1);
                if (NSS >= 2) p2 = fmaf(o, v2c[cf], p2);
                if (ST) {
                    if (OBF) ((unsigned short*)Y)[(size_t)r * ldy + cf * 16 + l15] = (unsigned short)f2bf(o);
                    else     Y[(size_t)r * ldy + cf * 16 + l15] = o;
                }
            }
            if (NSS >= 1) {
#pragma unroll
                for (int w = 1; w < 16; w <<= 1) {
                    p1 += __shfl_xor(p1, w, 64);
                    if (NSS >= 2) p2 += __shfl_xor(p2, w, 64);
                }
                if (l15 == 0) {
                    ss1[r] = p1 + sbv;
                    if (NSS >= 2) ss2[r] = p2;
                }
            }
        }
    }
}

// ---------------- dual-config K=128 MFMA GEMM (runtime epilogue flags) ----------------
struct MfmaCfg {
    const float* X; int ldx;
    const short* Wp;
    const float* bias;
    float* Y; int ldy; int M;
    int act, nss, obf;
    const float* v1; float* ss1;
    const float* v2; float* ss2;
    int nblocks;
};

__global__ __launch_bounds__(256, 2) void k_mfma2(MfmaCfg c0, MfmaCfg c1)
{
    constexpr int K = 128, KF = 4, KP = 136;
    __shared__ short Bs[2 * 128 * KP];
    const bool first = blockIdx.x < c0.nblocks;
    const MfmaCfg& c = first ? c0 : c1;
    const int bid = first ? blockIdx.x : blockIdx.x - c0.nblocks;
    const int tid = threadIdx.x;
    const int wave = tid >> 6, lane = tid & 63;
    const int l15 = lane & 15, quad = lane >> 4;
    const int wrow = bid * 128 + wave * 32;

    {
        const float4* src = (const float4*)c.Wp;
        float4* dst = (float4*)Bs;
        constexpr int total = 2 * 128 * KP / 8;
        for (int i = tid; i < total; i += 256) dst[i] = src[i];
    }

    v4f acc[2][8];
#pragma unroll
    for (int rf = 0; rf < 2; ++rf)
#pragma unroll
        for (int cf = 0; cf < 8; ++cf) acc[rf][cf] = (v4f){0.f, 0.f, 0.f, 0.f};

    v8s ah[2][KF], al[2][KF];
#pragma unroll
    for (int rf = 0; rf < 2; ++rf) {
        int r = wrow + rf * 16 + l15; if (r >= c.M) r = c.M - 1;
        const float* xp = c.X + (size_t)r * c.ldx + quad * 8;
#pragma unroll
        for (int kf = 0; kf < KF; ++kf) {
            float xv[8];
            *(float4*)&xv[0] = *(const float4*)(xp + kf * 32);
            *(float4*)&xv[4] = *(const float4*)(xp + kf * 32 + 4);
            split8(xv, ah[rf][kf], al[rf][kf]);
        }
    }
    __syncthreads();
#pragma unroll
    for (int kf = 0; kf < KF; ++kf) {
#pragma unroll
        for (int cf = 0; cf < 8; ++cf) {
            const short* bp = &Bs[(cf * 16 + l15) * KP + kf * 32 + quad * 8];
            v8s bh = *(const v8s*)bp;
            v8s bl = *(const v8s*)(bp + 128 * KP);
#pragma unroll
            for (int rf = 0; rf < 2; ++rf) {
                acc[rf][cf] = __builtin_amdgcn_mfma_f32_16x16x32_bf16(al[rf][kf], bh, acc[rf][cf], 0, 0, 0);
                acc[rf][cf] = __builtin_amdgcn_mfma_f32_16x16x32_bf16(ah[rf][kf], bl, acc[rf][cf], 0, 0, 0);
                acc[rf][cf] = __builtin_amdgcn_mfma_f32_16x16x32_bf16(ah[rf][kf], bh, acc[rf][cf], 0, 0, 0);
            }
        }
    }

    float bv[8], v1c[8], v2c[8];
#pragma unroll
    for (int cf = 0; cf < 8; ++cf) {
        int col = cf * 16 + l15;
        bv[cf] = c.bias ? c.bias[col] : 0.f;
        v1c[cf] = (c.nss >= 1) ? c.v1[col] : 0.f;
        v2c[cf] = (c.nss >= 2) ? c.v2[col] : 0.f;
    }

#pragma unroll
    for (int rf = 0; rf < 2; ++rf) {
#pragma unroll
        for (int reg = 0; reg < 4; ++reg) {
            int r = wrow + rf * 16 + quad * 4 + reg;
            if (r >= c.M) continue;
            float p1 = 0.f, p2 = 0.f;
#pragma unroll
            for (int cf = 0; cf < 8; ++cf) {
                float o = acc[rf][cf][reg] + bv[cf];
                if (c.act) o = o > 0.f ? o : 0.f;
                p1 = fmaf(o, v1c[cf], p1);
                p2 = fmaf(o, v2c[cf], p2);
                if (c.obf) ((unsigned short*)c.Y)[(size_t)r * c.ldy + cf * 16 + l15] = (unsigned short)f2bf(o);
                else       c.Y[(size_t)r * c.ldy + cf * 16 + l15] = o;
            }
            if (c.nss >= 1) {
#pragma unroll
                for (int w = 1; w < 16; w <<= 1) {
                    p1 += __shfl_xor(p1, w, 64);
                    p2 += __shfl_xor(p2, w, 64);
                }
                if (l15 == 0) {
                    c.ss1[r] = p1;
                    if (c.nss >= 2) c.ss2[r] = p2;
                }
            }
        }
    }
}

// ---------------- GAT aggregation: padded rows + analytic self-loop ----------------
template<int ELU, int U, int CAP>
__global__ __launch_bounds__(256) void k_aggregate(
    const int* __restrict__ deg, const int* __restrict__ esp,
    const unsigned short* __restrict__ hs, const float* __restrict__ ss,
    const float* __restrict__ sd, const float* __restrict__ bias,
    float* __restrict__ out, int ldy, int n, int loopn)
{
    int lane = threadIdx.x & 63;
    int wv = threadIdx.x >> 6;
    int d = blockIdx.x * 4 + wv;
    if (d >= n) return;
    int half = lane >> 5;
    int col = (lane & 31) * 4;
    const int* row = esp + (size_t)d * CAP;
    int i1 = deg[d]; if (i1 > CAP) i1 = CAP;
    float sdv = sd[d];
    float den = 0.f;
    float ax = 0.f, ay = 0.f, az = 0.f, aw = 0.f;
    if (half == 0 && d < loopn) {   // analytic self-loop (s = d), counted once
        ushort4 h = *(const ushort4*)(hs + (size_t)d * HH + col);
        float l = ss[d] + sdv;
        l = l < 0.f ? 0.2f * l : l;
        float e = __expf(l);
        den += e;
        ax = fmaf(e, bfu2f(h.x), ax);
        ay = fmaf(e, bfu2f(h.y), ay);
        az = fmaf(e, bfu2f(h.z), az);
        aw = fmaf(e, bfu2f(h.w), aw);
    }
    int i = 0;
    for (; i + 2 * U <= i1; i += 2 * U) {
        int s[U]; ushort4 h[U]; float sv[U];
#pragma unroll
        for (int u = 0; u < U; ++u) s[u] = row[i + 2 * u + half];
#pragma unroll
        for (int u = 0; u < U; ++u) h[u] = *(const ushort4*)(hs + (size_t)s[u] * HH + col);
#pragma unroll
        for (int u = 0; u < U; ++u) sv[u] = ss[s[u]];
#pragma unroll
        for (int u = 0; u < U; ++u) {
            float l = sv[u] + sdv;
            l = l < 0.f ? 0.2f * l : l;
            float e = __expf(l);
            den += e;
            ax = fmaf(e, bfu2f(h[u].x), ax);
            ay = fmaf(e, bfu2f(h[u].y), ay);
            az = fmaf(e, bfu2f(h[u].z), az);
            aw = fmaf(e, bfu2f(h[u].w), aw);
        }
    }
    if (i < i1) {
        int s[U]; ushort4 h[U]; float sv[U]; bool act[U];
#pragma unroll
        for (int u = 0; u < U; ++u) {
            int idx = i + 2 * u + half;
            act[u] = idx < i1;
            s[u] = row[act[u] ? idx : (i1 - 1)];
        }
#pragma unroll
        for (int u = 0; u < U; ++u) h[u] = *(const ushort4*)(hs + (size_t)s[u] * HH + col);
#pragma unroll
        for (int u = 0; u < U; ++u) sv[u] = ss[s[u]];
#pragma unroll
        for (int u = 0; u < U; ++u) {
            float l = sv[u] + sdv;
            l = l < 0.f ? 0.2f * l : l;
            float e = act[u] ? __expf(l) : 0.f;
            den += e;
            ax = fmaf(e, bfu2f(h[u].x), ax);
            ay = fmaf(e, bfu2f(h[u].y), ay);
            az = fmaf(e, bfu2f(h[u].z), az);
            aw = fmaf(e, bfu2f(h[u].w), aw);
        }
    }
    den += __shfl_xor(den, 32, 64);
    ax += __shfl_xor(ax, 32, 64);
    ay += __shfl_xor(ay, 32, 64);
    az += __shfl_xor(az, 32, 64);
    aw += __shfl_xor(aw, 32, 64);
    if (half == 0) {
        float4 b = *(const float4*)(bias + col);
        float inv = 1.f / (den + 1e-16f);
        float o0 = ax * inv + b.x;
        float o1 = ay * inv + b.y;
        float o2 = az * inv + b.z;
        float o3 = aw * inv + b.w;
        if (ELU) {
            o0 = o0 > 0.f ? o0 : expm1f(o0);
            o1 = o1 > 0.f ? o1 : expm1f(o1);
            o2 = o2 > 0.f ? o2 : expm1f(o2);
            o3 = o3 > 0.f ? o3 : expm1f(o3);
        }
        *(float4*)(out + (size_t)d * ldy + col) = make_float4(o0, o1, o2, o3);
    }
}

// ---------------- launcher ----------------
extern "C" void kernel_launch(void* const* d_in, const int* in_sizes, int n_in,
                              void* d_out, int out_size, void* d_ws, size_t ws_size,
                              hipStream_t stream)
{
    const float* artist = (const float*)d_in[0];
    const float* workf  = (const float*)d_in[1];
    const float* a_w1 = (const float*)d_in[2];  const float* a_b1 = (const float*)d_in[3];
    const float* a_w2 = (const float*)d_in[4];  const float* a_b2 = (const float*)d_in[5];
    const float* w_w1 = (const float*)d_in[6];  const float* w_b1 = (const float*)d_in[7];
    const float* w_w2 = (const float*)d_in[8];  const float* w_b2 = (const float*)d_in[9];
    const float* cr_W = (const float*)d_in[10]; const float* cr_b = (const float*)d_in[11];
    const float* cr_as = (const float*)d_in[12]; const float* cr_ad = (const float*)d_in[13];
    const float* in_W = (const float*)d_in[14]; const float* in_b = (const float*)d_in[15];
    const float* in_as = (const float*)d_in[16]; const float* in_ad = (const float*)d_in[17];
    const float* co_W = (const float*)d_in[18]; const float* co_b = (const float*)d_in[19];
    const float* co_as = (const float*)d_in[20]; const float* co_ad = (const float*)d_in[21];
    const float* p_w1 = (const float*)d_in[22]; const float* p_b1 = (const float*)d_in[23];
    const float* p_w2 = (const float*)d_in[24]; const float* p_b2 = (const float*)d_in[25];
    const float* p_w3 = (const float*)d_in[26]; const float* p_b3 = (const float*)d_in[27];
    const int* e_cr = (const int*)d_in[28];
    const int* e_cb = (const int*)d_in[29];
    const int* e_in = (const int*)d_in[30];
    const int* e_co = (const int*)d_in[31];

    char* wsp = (char*)d_ws;
    size_t off = 0;
    auto alloc = [&](size_t bytes) -> void* {
        void* p = wsp + off;
        off += (bytes + 255) / 256 * 256;
        return p;
    };
    float* ax   = (float*)alloc((size_t)NA * HH * 4);
    float* hsA  = (float*)alloc((size_t)NA * HH * 4);            // artist hidden
    float* wx   = (float*)alloc((size_t)NW * HH * 4);
    float* hs   = (float*)alloc((size_t)NW * HH * 4);            // work hidden + h1 [NA,256]
    unsigned short* hsb = (unsigned short*)alloc((size_t)NW * HH * 2);  // bf16 gather table
    float* comb = (float*)alloc((size_t)NA * 256 * 4);           // [au | ac]
    float* ss1 = (float*)alloc((size_t)NA * 4);
    float* sd1 = (float*)alloc((size_t)NW * 4);
    float* ss2 = (float*)alloc((size_t)NW * 4);
    float* sd2 = (float*)alloc((size_t)NW * 4);
    float* ss3 = (float*)alloc((size_t)NW * 4);
    float* sd3 = (float*)alloc((size_t)NA * 4);
    float* ss4 = (float*)alloc((size_t)NA * 4);
    float* sd4 = (float*)alloc((size_t)NA * 4);
    float* vd  = (float*)alloc(HH * 4);
    int* deg   = (int*)alloc((size_t)NTOT * 4);
    int* pad1  = (int*)alloc((size_t)NW * CAPW * 4);
    int* pad2  = (int*)alloc((size_t)NW * CAPW * 4);
    int* pad3  = (int*)alloc((size_t)NA * CAPA * 4);
    int* pad4  = (int*)alloc((size_t)NA * CAPA * 4);
    short* preW = (short*)alloc((size_t)10 * PSLOT * 2);
    (void)ws_size; (void)in_sizes; (void)n_in; (void)out_size;

    auto pre = [&](int m) { return preW + (size_t)m * PSLOT; };
    auto gg = [](int M) { return (M + 127) / 128; };
    const float* nf = nullptr;
    float* nfm = nullptr;

    // ---- prep args ----
    PrepArgs pa;
    pa.d[0] = {a_w1, HH, DA};
    pa.d[1] = {a_w2, HH, HH};
    pa.d[2] = {w_w1, HH, HH};
    pa.d[3] = {w_w2, HH, HH};
    pa.d[4] = {cr_W, HH, HH};
    pa.d[5] = {in_W, HH, HH};
    pa.d[6] = {co_W, HH, HH};
    pa.d[7] = {p_w1, 256, 256};
    pa.d[8] = {p_w1 + 128, 256, 256};
    pa.d[9] = {p_w2, HH, 256};
    pa.wvW = cr_W; pa.wvA = cr_ad; pa.vd = vd;

    // ---- edge sets (real edges only; loops analytic in aggregate) ----
    EdgeSets es;
    es.e[0] = e_cr; es.e[1] = e_in; es.e[2] = e_cb; es.e[3] = e_co;
    es.E[0] = E_CR; es.E[1] = E_IN; es.E[2] = E_CR; es.E[3] = E_CO;
    es.row[0] = ROW1; es.row[1] = ROW2; es.row[2] = ROW3; es.row[3] = ROW4;
    es.cum[0] = 0; es.cum[1] = E_CR; es.cum[2] = E_CR + E_IN;
    es.cum[3] = E_CR + E_IN + E_CR; es.cum[4] = ETOTR;
    es.pad[0] = pad1; es.pad[1] = pad2; es.pad[2] = pad3; es.pad[3] = pad4;
    es.cap[0] = CAPW; es.cap[1] = CAPW; es.cap[2] = CAPA; es.cap[3] = CAPA;

    (void)hipMemsetAsync(deg, 0, (size_t)NTOT * 4, stream);
    int nApp = (ETOTR + 1023) / 1024;
    k_prep_append<<<NPREP + nApp, 256, 0, stream>>>(pa, preW, es, deg);

    // ---- artist MLP layer 1 (K=64) ----
    k_mfma<DA, 1, 0, 1, 1, 0, 0><<<gg(NA), 256, 0, stream>>>(artist, DA, pre(0), a_b1, hsA, HH, NA, nf, nfm, nf, nfm, nf);

    // ---- fused: work MLP L1 (NW) + artist MLP L2 (NA, sd3 = ax@vd) ----
    {
        MfmaCfg c0 = {workf, HH, pre(2), w_b1, hs, HH, NW, 1, 0, 0, nf, nfm, nf, nfm, gg(NW)};
        MfmaCfg c1 = {hsA, HH, pre(1), a_b2, ax, HH, NA, 0, 1, 0, vd, sd3, nf, nfm, gg(NA)};
        k_mfma2<<<gg(NW) + gg(NA), 256, 0, stream>>>(c0, c1);
    }
    // ---- fused: work MLP L2 (NW, sd1 = wx@vd) + GAT1 GEMM (NA, ss1) ----
    {
        MfmaCfg c0 = {hs, HH, pre(3), w_b2, wx, HH, NW, 0, 1, 0, vd, sd1, nf, nfm, gg(NW)};
        MfmaCfg c1 = {ax, HH, pre(4), nullptr, (float*)hsb, HH, NA, 0, 1, 1, cr_as, ss1, nf, nfm, gg(NA)};
        k_mfma2<<<gg(NW) + gg(NA), 256, 0, stream>>>(c0, c1);
    }

    // ---- GAT1: creates (artists -> works), out wx, ELU, loops d<NA ----
    k_aggregate<1, 2, CAPW><<<(NW + 3) / 4, 256, 0, stream>>>(deg + ROW1, pad1, hsb, ss1, sd1, cr_b, wx, HH, NW, NA);

    // ---- GAT2: influences (works -> works), out wx, ELU ----
    k_mfma<HH, 0, 2, 1, 1, 1, 0><<<gg(NW), 256, 0, stream>>>(wx, HH, pre(5), nullptr, (float*)hsb, HH, NW, in_as, ss2, in_ad, sd2, nf);
    k_aggregate<1, 2, CAPW><<<(NW + 3) / 4, 256, 0, stream>>>(deg + ROW2, pad2, hsb, ss2, sd2, in_b, wx, HH, NW, NW);

    // ---- GAT3: created_by (works -> artists), out au = comb[:,0:128], NO elu ----
    k_mfma<HH, 0, 1, 1, 1, 1, 0><<<gg(NW), 256, 0, stream>>>(wx, HH, pre(4), nullptr, (float*)hsb, HH, NW, cr_as, ss3, nf, nfm, nf);
    k_aggregate<0, 4, CAPA><<<(NA + 3) / 4, 256, 0, stream>>>(deg + ROW3, pad3, hsb, ss3, sd3, cr_b, comb, 256, NA, NA);

    // ---- GAT4: collab (artists -> artists), out ac = comb[:,128:256], ELU ----
    k_mfma<HH, 0, 2, 1, 1, 1, 0><<<gg(NA), 256, 0, stream>>>(comb, 256, pre(6), nullptr, (float*)hsb, HH, NA, co_as, ss4, co_ad, sd4, nf);
    k_aggregate<1, 4, CAPA><<<(NA + 3) / 4, 256, 0, stream>>>(deg + ROW4, pad4, hsb, ss4, sd4, co_b, comb + 128, 256, NA, NA);

    // ---- predictor ----
    float* h1 = hs;
    k_mfma<256, 1, 0, 1, 0, 0, 1><<<2 * gg(NA), 256, 0, stream>>>(comb, 256, pre(7), p_b1, h1, 256, NA, nf, nfm, nf, nfm, nf);
    k_mfma<256, 1, 1, 0, 0, 0, 0><<<gg(NA), 256, 0, stream>>>(h1, 256, pre(9), p_b2, nfm, 0, NA, p_w3, (float*)d_out, nf, nfm, p_b3);
}

// Round 12
// 587.974 us; speedup vs baseline: 1.4778x; 1.0506x over previous
//
#include <hip/hip_runtime.h>
#include <hip/hip_bf16.h>
#include <cstddef>

#define NA 20000
#define NW 100000
#define HH 128
#define DA 64
#define E_CR 400000
#define E_IN 600000
#define E_CO 300000

#define ROW1 0
#define ROW2 (NW)
#define ROW3 (2 * NW)
#define ROW4 (2 * NW + NA)
#define NTOT (2 * NW + 2 * NA)
#define CAPW 40
#define CAPA 88
#define NPREP (10 * 128 + 1)

typedef short v8s __attribute__((ext_vector_type(8)));
typedef float v4f __attribute__((ext_vector_type(4)));

constexpr int PSLOT = 2 * 128 * 264;

__device__ inline short f2bf(float x) {
    union { float f; unsigned u; } c; c.f = x;
    unsigned r = c.u + 0x7fff + ((c.u >> 16) & 1);   // RNE
    return (short)(r >> 16);
}
__device__ inline float bf2f(short s) {
    union { unsigned u; float f; } c; c.u = ((unsigned)(unsigned short)s) << 16;
    return c.f;
}
__device__ inline float bfu2f(unsigned short s) {
    union { unsigned u; float f; } c; c.u = ((unsigned)s) << 16;
    return c.f;
}

__device__ inline void split8(const float* xv, v8s& h, v8s& l) {
#pragma unroll
    for (int p = 0; p < 4; ++p) {
        float2 xf; xf.x = xv[2 * p]; xf.y = xv[2 * p + 1];
        __hip_bfloat162 hb = __float22bfloat162_rn(xf);
        float2 hf = __bfloat1622float2(hb);
        float2 lf; lf.x = xf.x - hf.x; lf.y = xf.y - hf.y;
        __hip_bfloat162 lb = __float22bfloat162_rn(lf);
        union { __hip_bfloat162 b; short2 s; } uh, ul;
        uh.b = hb; ul.b = lb;
        h[2 * p] = uh.s.x; h[2 * p + 1] = uh.s.y;
        l[2 * p] = ul.s.x; l[2 * p + 1] = ul.s.y;
    }
}

// ---------------- padded-CSR append chunk (rides inside compute launches) ----------------
struct AppChunk { const int* e; int E; int* pad; int cap; int* deg; };

__device__ inline void do_append(const AppChunk& ap, int bid) {
    int b0 = bid * 1024 + threadIdx.x;
    int s[4], d[4]; bool ok[4];
#pragma unroll
    for (int u = 0; u < 4; ++u) {
        int i = b0 + u * 256;
        ok[u] = i < ap.E;
        s[u] = 0; d[u] = 0;
        if (ok[u]) { s[u] = ap.e[i]; d[u] = ap.e[ap.E + i]; }
    }
    int p[4];
#pragma unroll
    for (int u = 0; u < 4; ++u) if (ok[u]) p[u] = atomicAdd(&ap.deg[d[u]], 1);
#pragma unroll
    for (int u = 0; u < 4; ++u)
        if (ok[u] && p[u] < ap.cap)
            ap.pad[(size_t)d[u] * ap.cap + p[u]] = s[u];
}

// ---------------- fused weight-prep + append chunk ----------------
struct PrepDesc { const float* src; int ldw; int K; };
struct PrepArgs { PrepDesc d[10]; const float* wvW; const float* wvA; float* vd; };

__global__ __launch_bounds__(256) void k_prep_append(PrepArgs a, short* __restrict__ out,
                                                    AppChunk ap)
{
    if (blockIdx.x >= NPREP) { do_append(ap, blockIdx.x - NPREP); return; }
    if (blockIdx.x == NPREP - 1) {   // folded: vd = cr_W @ cr_ad
        __shared__ float sa[HH];
        int t = threadIdx.x;
        if (t < HH) sa[t] = a.wvA[t];
        __syncthreads();
        if (t < HH) {
            float s = 0.f;
            for (int jj = 0; jj < HH; ++jj) s += a.wvW[(size_t)t * HH + jj] * sa[jj];
            a.vd[t] = s;
        }
        return;
    }
    int m = blockIdx.x >> 7;
    int e = (blockIdx.x & 127) * 256 + threadIdx.x;
    PrepDesc dd = a.d[m];
    int K = dd.K;
    int KP = (K <= 128) ? K + 8 : K;
    if (e >= K * 128) return;
    int n = e & 127, k = e >> 7;
    float x = dd.src[(size_t)k * dd.ldw + n];
    short h = f2bf(x);
    short l = f2bf(x - bf2f(h));
    short* base = out + (size_t)m * PSLOT;
    base[n * KP + k] = h;
    base[128 * KP + n * KP + k] = l;
}

// ---------------- split-bf16 MFMA GEMM (compile-time config) ----------------
template<int K, int ACT, int NSS, int ST, int LDSB, int OBF, int DUAL>
__global__ __launch_bounds__(256, 2) void k_mfma(
    const float* __restrict__ X, int ldx,
    const short* __restrict__ Wp,
    const float* __restrict__ bias,
    float* __restrict__ Y, int ldy, int M,
    const float* __restrict__ v1, float* __restrict__ ss1,
    const float* __restrict__ v2, float* __restrict__ ss2,
    const float* __restrict__ sb)
{
    constexpr int KF = K / 32;
    constexpr int KP = LDSB ? K + 8 : K;
    __shared__ short Bs[LDSB ? 2 * 128 * (K + 8) : 8];
    const int tid = threadIdx.x;
    const int wave = tid >> 6, lane = tid & 63;
    const int l15 = lane & 15, quad = lane >> 4;
    int bid = blockIdx.x;
    if (DUAL) {
        int g0 = gridDim.x >> 1;
        if (bid >= g0) { bid -= g0; Wp += PSLOT; bias += 128; Y += 128; }
    }
    const int wrow = bid * 128 + wave * 32;

    if (LDSB) {
        const float4* src = (const float4*)Wp;
        float4* dst = (float4*)Bs;
        constexpr int total = 2 * 128 * KP / 8;
        for (int i = tid; i < total; i += 256) dst[i] = src[i];
    }

    v4f acc[2][8];
#pragma unroll
    for (int rf = 0; rf < 2; ++rf)
#pragma unroll
        for (int cf = 0; cf < 8; ++cf) acc[rf][cf] = (v4f){0.f, 0.f, 0.f, 0.f};

    if (LDSB) {
        v8s ah[2][KF], al[2][KF];
#pragma unroll
        for (int rf = 0; rf < 2; ++rf) {
            int r = wrow + rf * 16 + l15; if (r >= M) r = M - 1;
            const float* xp = X + (size_t)r * ldx + quad * 8;
#pragma unroll
            for (int kf = 0; kf < KF; ++kf) {
                float xv[8];
                *(float4*)&xv[0] = *(const float4*)(xp + kf * 32);
                *(float4*)&xv[4] = *(const float4*)(xp + kf * 32 + 4);
                split8(xv, ah[rf][kf], al[rf][kf]);
            }
        }
        __syncthreads();
#pragma unroll
        for (int kf = 0; kf < KF; ++kf) {
#pragma unroll
            for (int cf = 0; cf < 8; ++cf) {
                const short* bp = &Bs[(cf * 16 + l15) * KP + kf * 32 + quad * 8];
                v8s bh = *(const v8s*)bp;
                v8s bl = *(const v8s*)(bp + 128 * KP);
#pragma unroll
                for (int rf = 0; rf < 2; ++rf) {
                    acc[rf][cf] = __builtin_amdgcn_mfma_f32_16x16x32_bf16(al[rf][kf], bh, acc[rf][cf], 0, 0, 0);
                    acc[rf][cf] = __builtin_amdgcn_mfma_f32_16x16x32_bf16(ah[rf][kf], bl, acc[rf][cf], 0, 0, 0);
                    acc[rf][cf] = __builtin_amdgcn_mfma_f32_16x16x32_bf16(ah[rf][kf], bh, acc[rf][cf], 0, 0, 0);
                }
            }
        }
    } else {
        for (int kf = 0; kf < KF; ++kf) {
            v8s ah[2], al[2];
#pragma unroll
            for (int rf = 0; rf < 2; ++rf) {
                int r = wrow + rf * 16 + l15; if (r >= M) r = M - 1;
                const float* xp = X + (size_t)r * ldx + kf * 32 + quad * 8;
                float xv[8];
                *(float4*)&xv[0] = *(const float4*)xp;
                *(float4*)&xv[4] = *(const float4*)(xp + 4);
                split8(xv, ah[rf], al[rf]);
            }
#pragma unroll
            for (int cf = 0; cf < 8; ++cf) {
                const short* bp = Wp + (size_t)(cf * 16 + l15) * K + kf * 32 + quad * 8;
                v8s bh = *(const v8s*)bp;
                v8s bl = *(const v8s*)(bp + 128 * KP);
#pragma unroll
                for (int rf = 0; rf < 2; ++rf) {
                    acc[rf][cf] = __builtin_amdgcn_mfma_f32_16x16x32_bf16(al[rf], bh, acc[rf][cf], 0, 0, 0);
                    acc[rf][cf] = __builtin_amdgcn_mfma_f32_16x16x32_bf16(ah[rf], bl, acc[rf][cf], 0, 0, 0);
                    acc[rf][cf] = __builtin_amdgcn_mfma_f32_16x16x32_bf16(ah[rf], bh, acc[rf][cf], 0, 0, 0);
                }
            }
        }
    }

    float bv[8], v1c[8], v2c[8];
#pragma unroll
    for (int cf = 0; cf < 8; ++cf) {
        int col = cf * 16 + l15;
        bv[cf] = bias ? bias[col] : 0.f;
        if (NSS >= 1) v1c[cf] = v1[col];
        if (NSS >= 2) v2c[cf] = v2[col];
    }
    float sbv = (NSS >= 1 && sb) ? sb[0] : 0.f;

#pragma unroll
    for (int rf = 0; rf < 2; ++rf) {
#pragma unroll
        for (int reg = 0; reg < 4; ++reg) {
            int r = wrow + rf * 16 + quad * 4 + reg;
            if (r >= M) continue;
            float p1 = 0.f, p2 = 0.f;
#pragma unroll
            for (int cf = 0; cf < 8; ++cf) {
                float o = acc[rf][cf][reg] + bv[cf];
                if (ACT == 1) o = o > 0.f ? o : 0.f;
                if (NSS >= 1) p1 = fmaf(o, v1c[cf], p1);
                if (NSS >= 2) p2 = fmaf(o, v2c[cf], p2);
                if (ST) {
                    if (OBF) ((unsigned short*)Y)[(size_t)r * ldy + cf * 16 + l15] = (unsigned short)f2bf(o);
                    else     Y[(size_t)r * ldy + cf * 16 + l15] = o;
                }
            }
            if (NSS >= 1) {
#pragma unroll
                for (int w = 1; w < 16; w <<= 1) {
                    p1 += __shfl_xor(p1, w, 64);
                    if (NSS >= 2) p2 += __shfl_xor(p2, w, 64);
                }
                if (l15 == 0) {
                    ss1[r] = p1 + sbv;
                    if (NSS >= 2) ss2[r] = p2;
                }
            }
        }
    }
}

// ---------------- dual-config K=128 GEMM + optional append chunk ----------------
struct MfmaCfg {
    const float* X; int ldx;
    const short* Wp;
    const float* bias;
    float* Y; int ldy; int M;
    int act, nss, obf;
    const float* v1; float* ss1;
    const float* v2; float* ss2;
    int nblocks;
};

__global__ __launch_bounds__(256, 2) void k_mfma2(MfmaCfg c0, MfmaCfg c1, AppChunk ap)
{
    constexpr int K = 128, KF = 4, KP = 136;
    __shared__ short Bs[2 * 128 * KP];
    int bid = blockIdx.x;
    if (bid >= c0.nblocks + c1.nblocks) { do_append(ap, bid - c0.nblocks - c1.nblocks); return; }
    const bool first = bid < c0.nblocks;
    const MfmaCfg& c = first ? c0 : c1;
    if (!first) bid -= c0.nblocks;
    const int tid = threadIdx.x;
    const int wave = tid >> 6, lane = tid & 63;
    const int l15 = lane & 15, quad = lane >> 4;
    const int wrow = bid * 128 + wave * 32;

    {
        const float4* src = (const float4*)c.Wp;
        float4* dst = (float4*)Bs;
        constexpr int total = 2 * 128 * KP / 8;
        for (int i = tid; i < total; i += 256) dst[i] = src[i];
    }

    v4f acc[2][8];
#pragma unroll
    for (int rf = 0; rf < 2; ++rf)
#pragma unroll
        for (int cf = 0; cf < 8; ++cf) acc[rf][cf] = (v4f){0.f, 0.f, 0.f, 0.f};

    v8s ah[2][KF], al[2][KF];
#pragma unroll
    for (int rf = 0; rf < 2; ++rf) {
        int r = wrow + rf * 16 + l15; if (r >= c.M) r = c.M - 1;
        const float* xp = c.X + (size_t)r * c.ldx + quad * 8;
#pragma unroll
        for (int kf = 0; kf < KF; ++kf) {
            float xv[8];
            *(float4*)&xv[0] = *(const float4*)(xp + kf * 32);
            *(float4*)&xv[4] = *(const float4*)(xp + kf * 32 + 4);
            split8(xv, ah[rf][kf], al[rf][kf]);
        }
    }
    __syncthreads();
#pragma unroll
    for (int kf = 0; kf < KF; ++kf) {
#pragma unroll
        for (int cf = 0; cf < 8; ++cf) {
            const short* bp = &Bs[(cf * 16 + l15) * KP + kf * 32 + quad * 8];
            v8s bh = *(const v8s*)bp;
            v8s bl = *(const v8s*)(bp + 128 * KP);
#pragma unroll
            for (int rf = 0; rf < 2; ++rf) {
                acc[rf][cf] = __builtin_amdgcn_mfma_f32_16x16x32_bf16(al[rf][kf], bh, acc[rf][cf], 0, 0, 0);
                acc[rf][cf] = __builtin_amdgcn_mfma_f32_16x16x32_bf16(ah[rf][kf], bl, acc[rf][cf], 0, 0, 0);
                acc[rf][cf] = __builtin_amdgcn_mfma_f32_16x16x32_bf16(ah[rf][kf], bh, acc[rf][cf], 0, 0, 0);
            }
        }
    }

    float bv[8], v1c[8], v2c[8];
#pragma unroll
    for (int cf = 0; cf < 8; ++cf) {
        int col = cf * 16 + l15;
        bv[cf] = c.bias ? c.bias[col] : 0.f;
        v1c[cf] = (c.nss >= 1) ? c.v1[col] : 0.f;
        v2c[cf] = (c.nss >= 2) ? c.v2[col] : 0.f;
    }

#pragma unroll
    for (int rf = 0; rf < 2; ++rf) {
#pragma unroll
        for (int reg = 0; reg < 4; ++reg) {
            int r = wrow + rf * 16 + quad * 4 + reg;
            if (r >= c.M) continue;
            float p1 = 0.f, p2 = 0.f;
#pragma unroll
            for (int cf = 0; cf < 8; ++cf) {
                float o = acc[rf][cf][reg] + bv[cf];
                if (c.act) o = o > 0.f ? o : 0.f;
                p1 = fmaf(o, v1c[cf], p1);
                p2 = fmaf(o, v2c[cf], p2);
                if (c.obf) ((unsigned short*)c.Y)[(size_t)r * c.ldy + cf * 16 + l15] = (unsigned short)f2bf(o);
                else       c.Y[(size_t)r * c.ldy + cf * 16 + l15] = o;
            }
            if (c.nss >= 1) {
#pragma unroll
                for (int w = 1; w < 16; w <<= 1) {
                    p1 += __shfl_xor(p1, w, 64);
                    p2 += __shfl_xor(p2, w, 64);
                }
                if (l15 == 0) {
                    c.ss1[r] = p1;
                    if (c.nss >= 2) c.ss2[r] = p2;
                }
            }
        }
    }
}

// ---------------- GAT aggregation: padded rows + analytic self-loop ----------------
template<int ELU, int U, int CAP>
__global__ __launch_bounds__(256) void k_aggregate(
    const int* __restrict__ deg, const int* __restrict__ esp,
    const unsigned short* __restrict__ hs, const float* __restrict__ ss,
    const float* __restrict__ sd, const float* __restrict__ bias,
    float* __restrict__ out, int ldy, int n, int loopn)
{
    int lane = threadIdx.x & 63;
    int wv = threadIdx.x >> 6;
    int d = blockIdx.x * 4 + wv;
    if (d >= n) return;
    int half = lane >> 5;
    int col = (lane & 31) * 4;
    const int* row = esp + (size_t)d * CAP;
    int i1 = deg[d]; if (i1 > CAP) i1 = CAP;
    float sdv = sd[d];
    float den = 0.f;
    float ax = 0.f, ay = 0.f, az = 0.f, aw = 0.f;
    if (half == 0 && d < loopn) {   // analytic self-loop
        ushort4 h = *(const ushort4*)(hs + (size_t)d * HH + col);
        float l = ss[d] + sdv;
        l = l < 0.f ? 0.2f * l : l;
        float e = __expf(l);
        den += e;
        ax = fmaf(e, bfu2f(h.x), ax);
        ay = fmaf(e, bfu2f(h.y), ay);
        az = fmaf(e, bfu2f(h.z), az);
        aw = fmaf(e, bfu2f(h.w), aw);
    }
    int i = 0;
    for (; i + 2 * U <= i1; i += 2 * U) {
        int s[U]; ushort4 h[U]; float sv[U];
#pragma unroll
        for (int u = 0; u < U; ++u) s[u] = row[i + 2 * u + half];
#pragma unroll
        for (int u = 0; u < U; ++u) h[u] = *(const ushort4*)(hs + (size_t)s[u] * HH + col);
#pragma unroll
        for (int u = 0; u < U; ++u) sv[u] = ss[s[u]];
#pragma unroll
        for (int u = 0; u < U; ++u) {
            float l = sv[u] + sdv;
            l = l < 0.f ? 0.2f * l : l;
            float e = __expf(l);
            den += e;
            ax = fmaf(e, bfu2f(h[u].x), ax);
            ay = fmaf(e, bfu2f(h[u].y), ay);
            az = fmaf(e, bfu2f(h[u].z), az);
            aw = fmaf(e, bfu2f(h[u].w), aw);
        }
    }
    if (i < i1) {
        int s[U]; ushort4 h[U]; float sv[U]; bool act[U];
#pragma unroll
        for (int u = 0; u < U; ++u) {
            int idx = i + 2 * u + half;
            act[u] = idx < i1;
            s[u] = row[act[u] ? idx : (i1 - 1)];
        }
#pragma unroll
        for (int u = 0; u < U; ++u) h[u] = *(const ushort4*)(hs + (size_t)s[u] * HH + col);
#pragma unroll
        for (int u = 0; u < U; ++u) sv[u] = ss[s[u]];
#pragma unroll
        for (int u = 0; u < U; ++u) {
            float l = sv[u] + sdv;
            l = l < 0.f ? 0.2f * l : l;
            float e = act[u] ? __expf(l) : 0.f;
            den += e;
            ax = fmaf(e, bfu2f(h[u].x), ax);
            ay = fmaf(e, bfu2f(h[u].y), ay);
            az = fmaf(e, bfu2f(h[u].z), az);
            aw = fmaf(e, bfu2f(h[u].w), aw);
        }
    }
    den += __shfl_xor(den, 32, 64);
    ax += __shfl_xor(ax, 32, 64);
    ay += __shfl_xor(ay, 32, 64);
    az += __shfl_xor(az, 32, 64);
    aw += __shfl_xor(aw, 32, 64);
    if (half == 0) {
        float4 b = *(const float4*)(bias + col);
        float inv = 1.f / (den + 1e-16f);
        float o0 = ax * inv + b.x;
        float o1 = ay * inv + b.y;
        float o2 = az * inv + b.z;
        float o3 = aw * inv + b.w;
        if (ELU) {
            o0 = o0 > 0.f ? o0 : expm1f(o0);
            o1 = o1 > 0.f ? o1 : expm1f(o1);
            o2 = o2 > 0.f ? o2 : expm1f(o2);
            o3 = o3 > 0.f ? o3 : expm1f(o3);
        }
        *(float4*)(out + (size_t)d * ldy + col) = make_float4(o0, o1, o2, o3);
    }
}

// ---------------- launcher ----------------
extern "C" void kernel_launch(void* const* d_in, const int* in_sizes, int n_in,
                              void* d_out, int out_size, void* d_ws, size_t ws_size,
                              hipStream_t stream)
{
    const float* artist = (const float*)d_in[0];
    const float* workf  = (const float*)d_in[1];
    const float* a_w1 = (const float*)d_in[2];  const float* a_b1 = (const float*)d_in[3];
    const float* a_w2 = (const float*)d_in[4];  const float* a_b2 = (const float*)d_in[5];
    const float* w_w1 = (const float*)d_in[6];  const float* w_b1 = (const float*)d_in[7];
    const float* w_w2 = (const float*)d_in[8];  const float* w_b2 = (const float*)d_in[9];
    const float* cr_W = (const float*)d_in[10]; const float* cr_b = (const float*)d_in[11];
    const float* cr_as = (const float*)d_in[12]; const float* cr_ad = (const float*)d_in[13];
    const float* in_W = (const float*)d_in[14]; const float* in_b = (const float*)d_in[15];
    const float* in_as = (const float*)d_in[16]; const float* in_ad = (const float*)d_in[17];
    const float* co_W = (const float*)d_in[18]; const float* co_b = (const float*)d_in[19];
    const float* co_as = (const float*)d_in[20]; const float* co_ad = (const float*)d_in[21];
    const float* p_w1 = (const float*)d_in[22]; const float* p_b1 = (const float*)d_in[23];
    const float* p_w2 = (const float*)d_in[24]; const float* p_b2 = (const float*)d_in[25];
    const float* p_w3 = (const float*)d_in[26]; const float* p_b3 = (const float*)d_in[27];
    const int* e_cr = (const int*)d_in[28];
    const int* e_cb = (const int*)d_in[29];
    const int* e_in = (const int*)d_in[30];
    const int* e_co = (const int*)d_in[31];

    char* wsp = (char*)d_ws;
    size_t off = 0;
    auto alloc = [&](size_t bytes) -> void* {
        void* p = wsp + off;
        off += (bytes + 255) / 256 * 256;
        return p;
    };
    float* ax   = (float*)alloc((size_t)NA * HH * 4);
    float* hsA  = (float*)alloc((size_t)NA * HH * 4);
    float* wx   = (float*)alloc((size_t)NW * HH * 4);
    float* hs   = (float*)alloc((size_t)NW * HH * 4);            // work hidden + h1 [NA,256]
    unsigned short* hsb = (unsigned short*)alloc((size_t)NW * HH * 2);
    float* comb = (float*)alloc((size_t)NA * 256 * 4);           // [au | ac]
    float* ss1 = (float*)alloc((size_t)NA * 4);
    float* sd1 = (float*)alloc((size_t)NW * 4);
    float* ss2 = (float*)alloc((size_t)NW * 4);
    float* sd2 = (float*)alloc((size_t)NW * 4);
    float* ss3 = (float*)alloc((size_t)NW * 4);
    float* sd3 = (float*)alloc((size_t)NA * 4);
    float* ss4 = (float*)alloc((size_t)NA * 4);
    float* sd4 = (float*)alloc((size_t)NA * 4);
    float* vd  = (float*)alloc(HH * 4);
    int* deg   = (int*)alloc((size_t)NTOT * 4);
    int* pad1  = (int*)alloc((size_t)NW * CAPW * 4);
    int* pad2  = (int*)alloc((size_t)NW * CAPW * 4);
    int* pad3  = (int*)alloc((size_t)NA * CAPA * 4);
    int* pad4  = (int*)alloc((size_t)NA * CAPA * 4);
    short* preW = (short*)alloc((size_t)10 * PSLOT * 2);
    (void)ws_size; (void)in_sizes; (void)n_in; (void)out_size;

    auto pre = [&](int m) { return preW + (size_t)m * PSLOT; };
    auto gg = [](int M) { return (M + 127) / 128; };
    auto apb = [](int E) { return (E + 1023) / 1024; };
    const float* nf = nullptr;
    float* nfm = nullptr;

    PrepArgs pa;
    pa.d[0] = {a_w1, HH, DA};
    pa.d[1] = {a_w2, HH, HH};
    pa.d[2] = {w_w1, HH, HH};
    pa.d[3] = {w_w2, HH, HH};
    pa.d[4] = {cr_W, HH, HH};
    pa.d[5] = {in_W, HH, HH};
    pa.d[6] = {co_W, HH, HH};
    pa.d[7] = {p_w1, 256, 256};
    pa.d[8] = {p_w1 + 128, 256, 256};
    pa.d[9] = {p_w2, HH, 256};
    pa.wvW = cr_W; pa.wvA = cr_ad; pa.vd = vd;

    AppChunk ap1 = {e_cr, E_CR, pad1, CAPW, deg + ROW1};
    AppChunk ap2 = {e_in, E_IN, pad2, CAPW, deg + ROW2};
    AppChunk ap3 = {e_cb, E_CR, pad3, CAPA, deg + ROW3};
    AppChunk ap4 = {e_co, E_CO, pad4, CAPA, deg + ROW4};
    AppChunk ap0 = {nullptr, 0, nullptr, 1, nullptr};

    (void)hipMemsetAsync(deg, 0, (size_t)NTOT * 4, stream);

    // L1: weight prep + append(pad1)
    k_prep_append<<<NPREP + apb(E_CR), 256, 0, stream>>>(pa, preW, ap1);

    // L2: artist MLP layer 1 (K=64)
    k_mfma<DA, 1, 0, 1, 1, 0, 0><<<gg(NA), 256, 0, stream>>>(artist, DA, pre(0), a_b1, hsA, HH, NA, nf, nfm, nf, nfm, nf);

    // L3: work MLP L1 (NW) + artist MLP L2 (NA, sd3) + append(pad2)
    {
        MfmaCfg c0 = {workf, HH, pre(2), w_b1, hs, HH, NW, 1, 0, 0, nf, nfm, nf, nfm, gg(NW)};
        MfmaCfg c1 = {hsA, HH, pre(1), a_b2, ax, HH, NA, 0, 1, 0, vd, sd3, nf, nfm, gg(NA)};
        k_mfma2<<<gg(NW) + gg(NA) + apb(E_IN), 256, 0, stream>>>(c0, c1, ap2);
    }
    // L4: work MLP L2 (NW, sd1) + GAT1 GEMM (NA, ss1) + append(pad3)
    {
        MfmaCfg c0 = {hs, HH, pre(3), w_b2, wx, HH, NW, 0, 1, 0, vd, sd1, nf, nfm, gg(NW)};
        MfmaCfg c1 = {ax, HH, pre(4), nullptr, (float*)hsb, HH, NA, 0, 1, 1, cr_as, ss1, nf, nfm, gg(NA)};
        k_mfma2<<<gg(NW) + gg(NA) + apb(E_CR), 256, 0, stream>>>(c0, c1, ap3);
    }

    // L5: GAT1 aggregate (creates: artists -> works), out wx, ELU, loops d<NA
    k_aggregate<1, 2, CAPW><<<(NW + 3) / 4, 256, 0, stream>>>(deg + ROW1, pad1, hsb, ss1, sd1, cr_b, wx, HH, NW, NA);

    // L6: GAT2 GEMM (NW, ss2/sd2) + append(pad4)
    {
        MfmaCfg c0 = {wx, HH, pre(5), nullptr, (float*)hsb, HH, NW, 0, 2, 1, in_as, ss2, in_ad, sd2, gg(NW)};
        MfmaCfg c1 = {nullptr, 0, nullptr, nullptr, nullptr, 0, 0, 0, 0, 0, nf, nfm, nf, nfm, 0};
        k_mfma2<<<gg(NW) + apb(E_CO), 256, 0, stream>>>(c0, c1, ap4);
    }
    // L7: GAT2 aggregate
    k_aggregate<1, 2, CAPW><<<(NW + 3) / 4, 256, 0, stream>>>(deg + ROW2, pad2, hsb, ss2, sd2, in_b, wx, HH, NW, NW);

    // L8: GAT3 GEMM
    k_mfma<HH, 0, 1, 1, 1, 1, 0><<<gg(NW), 256, 0, stream>>>(wx, HH, pre(4), nullptr, (float*)hsb, HH, NW, cr_as, ss3, nf, nfm, nf);
    // L9: GAT3 aggregate -> au = comb[:,0:128], NO elu
    k_aggregate<0, 4, CAPA><<<(NA + 3) / 4, 256, 0, stream>>>(deg + ROW3, pad3, hsb, ss3, sd3, cr_b, comb, 256, NA, NA);

    // L10: GAT4 GEMM
    k_mfma<HH, 0, 2, 1, 1, 1, 0><<<gg(NA), 256, 0, stream>>>(comb, 256, pre(6), nullptr, (float*)hsb, HH, NA, co_as, ss4, co_ad, sd4, nf);
    // L11: GAT4 aggregate -> ac = comb[:,128:256], ELU
    k_aggregate<1, 4, CAPA><<<(NA + 3) / 4, 256, 0, stream>>>(deg + ROW4, pad4, hsb, ss4, sd4, co_b, comb + 128, 256, NA, NA);

    // L12/L13: predictor
    float* h1 = hs;
    k_mfma<256, 1, 0, 1, 0, 0, 1><<<2 * gg(NA), 256, 0, stream>>>(comb, 256, pre(7), p_b1, h1, 256, NA, nf, nfm, nf, nfm, nf);
    k_mfma<256, 1, 1, 0, 0, 0, 0><<<gg(NA), 256, 0, stream>>>(h1, 256, pre(9), p_b2, nfm, 0, NA, p_w3, (float*)d_out, nf, nfm, p_b3);
}